// Round 2
// baseline (1092.074 us; speedup 1.0000x reference)
//
#include <hip/hip_runtime.h>
#include <cstdint>
#include <cstddef>

// ---------------- constants ----------------
#define DM   1024          // model dim
#define NT   8192          // B*L tokens
#define HD   256
#define BM 128
#define BN 128
#define BK 32

typedef __attribute__((ext_vector_type(4))) float f32x4;
typedef __attribute__((ext_vector_type(8))) short bf16x8;

__device__ __forceinline__ unsigned short f2bf(float f) {
    union { float f; uint32_t u; } v; v.f = f;
    return (unsigned short)((v.u + 0x7fffu + ((v.u >> 16) & 1u)) >> 16);
}
__device__ __forceinline__ float bf2f(unsigned short h) {
    union { uint32_t u; float f; } v; v.u = ((uint32_t)h) << 16;
    return v.f;
}

struct Ptr4 { const float* p[4]; };
struct Mask4 { const int* p[4]; };

// ---------------- prep kernels ----------------
__global__ void cvt_f32_to_bf16(const float* __restrict__ src,
                                unsigned short* __restrict__ dst, int n4) {
    int i = blockIdx.x * blockDim.x + threadIdx.x;
    if (i >= n4) return;
    float4 v = reinterpret_cast<const float4*>(src)[i];
    ushort4 o;
    o.x = f2bf(v.x); o.y = f2bf(v.y); o.z = f2bf(v.z); o.w = f2bf(v.w);
    reinterpret_cast<ushort4*>(dst)[i] = o;
}

// src fp32 [K][Nc] row-major  ->  dst bf16 [Nc][K] row-major (transposed)
__global__ void transpose_cvt(const float* __restrict__ src,
                              unsigned short* __restrict__ dst, int K, int Nc) {
    __shared__ float tile[32][33];
    const int n0 = blockIdx.x * 32, k0 = blockIdx.y * 32;
    const int tx = threadIdx.x & 31, ty = threadIdx.x >> 5;   // 32 x 8
#pragma unroll
    for (int i = 0; i < 4; ++i) {
        int k = ty + i * 8;
        tile[k][tx] = src[(size_t)(k0 + k) * Nc + n0 + tx];
    }
    __syncthreads();
#pragma unroll
    for (int i = 0; i < 4; ++i) {
        int n = ty + i * 8;
        dst[(size_t)(n0 + n) * K + k0 + tx] = f2bf(tile[tx][n]);
    }
}

// ---------------- GEMM: C[M][Nc] = A[M][K] x Bt[Nc][K]^T ----------------
// EPI: 0 = (acc+bias)*mask -> bf16   (masked modality projection)
//      1 = acc+bias        -> bf16
//      2 = gelu(acc+bias)  -> bf16   (exact erf GELU)
//      3 = acc+bias        -> f32
__device__ __forceinline__ void gload16(const void* g, void* l) {
    __builtin_amdgcn_global_load_lds(
        (const __attribute__((address_space(1))) void*)g,
        (__attribute__((address_space(3))) void*)l, 16, 0, 0);
}

template <int EPI>
__global__ void gemm_bt(const unsigned short* __restrict__ A,
                        const unsigned short* __restrict__ Bt,
                        void* __restrict__ out, Ptr4 bias, Mask4 masks,
                        int M, int Nc, int K) {
    __shared__ __attribute__((aligned(16))) unsigned short Als[BM * BK];
    __shared__ __attribute__((aligned(16))) unsigned short Bls[BN * BK];
    const int tid = threadIdx.x;
    const int wave = tid >> 6, lane = tid & 63;
    const int tileM = blockIdx.y * BM, tileN = blockIdx.x * BN;
    const int wr = wave >> 1, wc = wave & 1;

    f32x4 acc[4][4] = {};

    const int sr = tid >> 2;            // row within 64-row half
    const int sc = (tid & 3) * 8;       // k element offset
    const unsigned short* aSrc0 = A + (size_t)(tileM + sr) * K + sc;
    const unsigned short* aSrc1 = A + (size_t)(tileM + 64 + sr) * K + sc;
    const unsigned short* bSrc0 = Bt + (size_t)(tileN + sr) * K + sc;
    const unsigned short* bSrc1 = Bt + (size_t)(tileN + 64 + sr) * K + sc;
    unsigned short* aDst0 = &Als[wave * 512];
    unsigned short* aDst1 = &Als[2048 + wave * 512];
    unsigned short* bDst0 = &Bls[wave * 512];
    unsigned short* bDst1 = &Bls[2048 + wave * 512];

    const int la = lane & 15;
    const int lb = (lane >> 4) * 8;

    for (int k0 = 0; k0 < K; k0 += BK) {
        gload16(aSrc0 + k0, aDst0);
        gload16(aSrc1 + k0, aDst1);
        gload16(bSrc0 + k0, bDst0);
        gload16(bSrc1 + k0, bDst1);
        __syncthreads();
        bf16x8 af[4], bfr[4];
#pragma unroll
        for (int m = 0; m < 4; ++m)
            af[m] = *reinterpret_cast<const bf16x8*>(&Als[(wr * 64 + m * 16 + la) * BK + lb]);
#pragma unroll
        for (int n = 0; n < 4; ++n)
            bfr[n] = *reinterpret_cast<const bf16x8*>(&Bls[(wc * 64 + n * 16 + la) * BK + lb]);
#pragma unroll
        for (int m = 0; m < 4; ++m)
#pragma unroll
            for (int n = 0; n < 4; ++n)
                acc[m][n] = __builtin_amdgcn_mfma_f32_16x16x32_bf16(af[m], bfr[n], acc[m][n], 0, 0, 0);
        __syncthreads();
    }

    const float* bp = bias.p[tileN >> 10];
    const int rowT = tileM + wr * 64 + (lane >> 4) * 4;
    const int colT = tileN + wc * 64;
    unsigned short* outB = (unsigned short*)out;
    float* outF = (float*)out;

    float mv[4][4];
    if constexpr (EPI == 0) {
        const int* mp = masks.p[tileN >> 10];
#pragma unroll
        for (int m = 0; m < 4; ++m)
#pragma unroll
            for (int i = 0; i < 4; ++i)
                mv[m][i] = (float)mp[rowT + m * 16 + i];
    }

#pragma unroll
    for (int n = 0; n < 4; ++n) {
        const int gcol = colT + n * 16 + la;
        const float bv = bp[gcol & (DM - 1)];
#pragma unroll
        for (int m = 0; m < 4; ++m) {
#pragma unroll
            for (int i = 0; i < 4; ++i) {
                const int grow = rowT + m * 16 + i;
                float val = acc[m][n][i] + bv;
                if constexpr (EPI == 0) {
                    val *= mv[m][i];
                    outB[(size_t)grow * Nc + gcol] = f2bf(val);
                } else if constexpr (EPI == 1) {
                    outB[(size_t)grow * Nc + gcol] = f2bf(val);
                } else if constexpr (EPI == 2) {
                    val = 0.5f * val * (1.0f + erff(val * 0.70710678118654752f));
                    outB[(size_t)grow * Nc + gcol] = f2bf(val);
                } else {
                    outF[(size_t)grow * Nc + gcol] = val;
                }
            }
        }
    }
}

// ---------------- tiny 4-token attention ----------------
// qkv bf16 [T*4][3072] (q|k|v each 1024 cols); ctx bf16 [T*4][1024]
__global__ void attn4(const unsigned short* __restrict__ qkv,
                      unsigned short* __restrict__ ctx) {
    const int n = blockIdx.x;
    const int h = threadIdx.x >> 6;      // wave = head
    const int lane = threadIdx.x & 63;   // 4 elems per lane (hd=256)
    const size_t base = (size_t)n * 4 * 3072 + h * HD + lane * 4;

    float q[4][4], k[4][4], v[4][4];
#pragma unroll
    for (int m = 0; m < 4; ++m) {
        ushort4 uq = *reinterpret_cast<const ushort4*>(&qkv[base + (size_t)m * 3072]);
        ushort4 uk = *reinterpret_cast<const ushort4*>(&qkv[base + (size_t)m * 3072 + 1024]);
        ushort4 uv = *reinterpret_cast<const ushort4*>(&qkv[base + (size_t)m * 3072 + 2048]);
        q[m][0] = bf2f(uq.x); q[m][1] = bf2f(uq.y); q[m][2] = bf2f(uq.z); q[m][3] = bf2f(uq.w);
        k[m][0] = bf2f(uk.x); k[m][1] = bf2f(uk.y); k[m][2] = bf2f(uk.z); k[m][3] = bf2f(uk.w);
        v[m][0] = bf2f(uv.x); v[m][1] = bf2f(uv.y); v[m][2] = bf2f(uv.z); v[m][3] = bf2f(uv.w);
    }

    float s[4][4];
#pragma unroll
    for (int qi = 0; qi < 4; ++qi)
#pragma unroll
        for (int ki = 0; ki < 4; ++ki)
            s[qi][ki] = q[qi][0] * k[ki][0] + q[qi][1] * k[ki][1] +
                        q[qi][2] * k[ki][2] + q[qi][3] * k[ki][3];
#pragma unroll
    for (int off = 32; off >= 1; off >>= 1) {
#pragma unroll
        for (int qi = 0; qi < 4; ++qi)
#pragma unroll
            for (int ki = 0; ki < 4; ++ki)
                s[qi][ki] += __shfl_xor(s[qi][ki], off, 64);
    }

#pragma unroll
    for (int qi = 0; qi < 4; ++qi) {
        float s0 = s[qi][0] * 0.0625f, s1 = s[qi][1] * 0.0625f;
        float s2 = s[qi][2] * 0.0625f, s3 = s[qi][3] * 0.0625f;
        float mx = fmaxf(fmaxf(s0, s1), fmaxf(s2, s3));
        float e0 = __expf(s0 - mx), e1 = __expf(s1 - mx);
        float e2 = __expf(s2 - mx), e3 = __expf(s3 - mx);
        float inv = 1.0f / (e0 + e1 + e2 + e3);
        e0 *= inv; e1 *= inv; e2 *= inv; e3 *= inv;
        ushort4 o;
        o.x = f2bf(e0 * v[0][0] + e1 * v[1][0] + e2 * v[2][0] + e3 * v[3][0]);
        o.y = f2bf(e0 * v[0][1] + e1 * v[1][1] + e2 * v[2][1] + e3 * v[3][1]);
        o.z = f2bf(e0 * v[0][2] + e1 * v[1][2] + e2 * v[2][2] + e3 * v[3][2]);
        o.w = f2bf(e0 * v[0][3] + e1 * v[1][3] + e2 * v[2][3] + e3 * v[3][3]);
        *reinterpret_cast<ushort4*>(&ctx[(size_t)(n * 4 + qi) * 1024 + h * HD + lane * 4]) = o;
    }
}

// ---------------- residual + LayerNorm ----------------
__global__ void resid_ln(const float* __restrict__ cons, const float* __restrict__ feat,
                         const float* __restrict__ g, const float* __restrict__ b,
                         float* __restrict__ out) {
    const int row = blockIdx.x;
    const int t = threadIdx.x;          // 256 threads x 4 floats
    const size_t base = (size_t)row * DM + t * 4;
    float4 c = *reinterpret_cast<const float4*>(&cons[base]);
    float4 f = *reinterpret_cast<const float4*>(&feat[base]);
    float y0 = c.x + f.x, y1 = c.y + f.y, y2 = c.z + f.z, y3 = c.w + f.w;
    float sum = y0 + y1 + y2 + y3;
    float sq = y0 * y0 + y1 * y1 + y2 * y2 + y3 * y3;
#pragma unroll
    for (int off = 32; off >= 1; off >>= 1) {
        sum += __shfl_xor(sum, off, 64);
        sq += __shfl_xor(sq, off, 64);
    }
    __shared__ float rs[4], rq[4];
    const int wv = t >> 6, ln = t & 63;
    if (ln == 0) { rs[wv] = sum; rq[wv] = sq; }
    __syncthreads();
    sum = rs[0] + rs[1] + rs[2] + rs[3];
    sq = rq[0] + rq[1] + rq[2] + rq[3];
    const float mu = sum * (1.0f / DM);
    const float var = sq * (1.0f / DM) - mu * mu;
    const float rstd = rsqrtf(var + 1e-5f);
    float4 gg = *reinterpret_cast<const float4*>(&g[t * 4]);
    float4 bb = *reinterpret_cast<const float4*>(&b[t * 4]);
    float4 o;
    o.x = (y0 - mu) * rstd * gg.x + bb.x;
    o.y = (y1 - mu) * rstd * gg.y + bb.y;
    o.z = (y2 - mu) * rstd * gg.z + bb.z;
    o.w = (y3 - mu) * rstd * gg.w + bb.w;
    *reinterpret_cast<float4*>(&out[base]) = o;
}

// ---------------- launch ----------------
extern "C" void kernel_launch(void* const* d_in, const int* in_sizes, int n_in,
                              void* d_out, int out_size, void* d_ws, size_t ws_size,
                              hipStream_t stream) {
    (void)in_sizes; (void)n_in; (void)out_size;
    const float* feat = (const float*)d_in[0];
    const int* am = (const int*)d_in[1];
    const int* dmk = (const int*)d_in[2];
    const int* em = (const int*)d_in[3];
    const int* hmk = (const int*)d_in[4];
    const float* Wa = (const float*)d_in[5];  const float* ba = (const float*)d_in[6];
    const float* Wd = (const float*)d_in[7];  const float* bd = (const float*)d_in[8];
    const float* We = (const float*)d_in[9];  const float* be = (const float*)d_in[10];
    const float* Wh = (const float*)d_in[11]; const float* bh = (const float*)d_in[12];
    const float* Wq = (const float*)d_in[13]; const float* bq = (const float*)d_in[14];
    const float* Wk = (const float*)d_in[15]; const float* bk = (const float*)d_in[16];
    const float* Wv = (const float*)d_in[17]; const float* bv = (const float*)d_in[18];
    const float* Wo = (const float*)d_in[19]; const float* bo = (const float*)d_in[20];
    const float* Wg1 = (const float*)d_in[21]; const float* bg1 = (const float*)d_in[22];
    const float* Wg2 = (const float*)d_in[23]; const float* bg2 = (const float*)d_in[24];
    const float* lng = (const float*)d_in[25]; const float* lnb = (const float*)d_in[26];

    char* ws = (char*)d_ws;
    size_t off = 0;
    auto take = [&](size_t bytes) -> char* {
        char* r = ws + off;
        off = (off + bytes + 255) & ~(size_t)255;
        return r;
    };
    // ---- fixed allocations: ~54.6 MB ----
    unsigned short* featB = (unsigned short*)take((size_t)NT * DM * 2);        // 16.8MB
    unsigned short* Bt1   = (unsigned short*)take((size_t)4 * DM * DM * 2);    // 8.4MB
    unsigned short* Btqkv = (unsigned short*)take((size_t)3 * DM * DM * 2);    // 6.3MB
    unsigned short* Bto   = (unsigned short*)take((size_t)DM * DM * 2);        // 2.1MB
    unsigned short* Btg1  = (unsigned short*)take((size_t)2 * DM * 4 * DM * 2);// 16.8MB
    unsigned short* Btg2  = (unsigned short*)take((size_t)DM * 2 * DM * 2);    // 4.2MB

    // ---- chunked activation buffers: 40KB/token, pick largest T<=2048 that fits ----
    const size_t fixed = off;
    const size_t avail = (ws_size > fixed) ? (ws_size - fixed) : 0;
    int T = 2048;
    while (T > 128 && ((size_t)T * 40960 + 4096) > avail) T >>= 1;
    unsigned short* bufA = (unsigned short*)take((size_t)T * 4096 * 2);        // x / attended
    unsigned short* bufB = (unsigned short*)take((size_t)T * 4 * 3072 * 2);    // qkv / consensus(f32)
    unsigned short* bufC = (unsigned short*)take((size_t)T * 4 * 1024 * 2);    // ctx / gelu-h

    // --- prep: convert features, transpose+convert weights to bf16 [N][K] ---
    cvt_f32_to_bf16<<<dim3((NT * DM / 4 + 255) / 256), dim3(256), 0, stream>>>(
        feat, featB, NT * DM / 4);
    auto tl = [&](const float* src, unsigned short* dst, int K, int Nc) {
        transpose_cvt<<<dim3(Nc / 32, K / 32), dim3(256), 0, stream>>>(src, dst, K, Nc);
    };
    tl(Wa, Bt1, DM, DM);
    tl(Wd, Bt1 + (size_t)DM * DM, DM, DM);
    tl(We, Bt1 + (size_t)2 * DM * DM, DM, DM);
    tl(Wh, Bt1 + (size_t)3 * DM * DM, DM, DM);
    tl(Wq, Btqkv, DM, DM);
    tl(Wk, Btqkv + (size_t)DM * DM, DM, DM);
    tl(Wv, Btqkv + (size_t)2 * DM * DM, DM, DM);
    tl(Wo, Bto, DM, DM);
    tl(Wg1, Btg1, 4 * DM, 2 * DM);
    tl(Wg2, Btg2, 2 * DM, DM);

    Ptr4 b1{{ba, bd, be, bh}};
    Ptr4 bqkv{{bq, bk, bv, nullptr}};
    Ptr4 bo4{{bo, nullptr, nullptr, nullptr}};
    Ptr4 bg14{{bg1, bg1 + DM, nullptr, nullptr}};
    Ptr4 bg24{{bg2, nullptr, nullptr, nullptr}};
    Mask4 mnull{{nullptr, nullptr, nullptr, nullptr}};

    const int nch = NT / T;
    for (int c = 0; c < nch; ++c) {
        const int t0 = c * T;
        Mask4 mk{{am + t0, dmk + t0, em + t0, hmk + t0}};
        // 1) masked modality projections -> bufA = x bf16 [T][4096]
        gemm_bt<0><<<dim3(4 * DM / BN, T / BM), dim3(256), 0, stream>>>(
            featB + (size_t)t0 * DM, Bt1, (void*)bufA, b1, mk, T, 4 * DM, DM);
        // 2) QKV -> bufB = qkv bf16 [4T][3072]
        gemm_bt<1><<<dim3(3 * DM / BN, 4 * T / BM), dim3(256), 0, stream>>>(
            bufA, Btqkv, (void*)bufB, bqkv, mnull, 4 * T, 3 * DM, DM);
        // 3) attention over 4 modality tokens -> bufC = ctx bf16 [4T][1024]
        attn4<<<dim3(T), dim3(256), 0, stream>>>(bufB, bufC);
        // 4) output projection -> bufA = attended bf16 [4T][1024] = [T][4096]
        gemm_bt<1><<<dim3(DM / BN, 4 * T / BM), dim3(256), 0, stream>>>(
            bufC, Bto, (void*)bufA, bo4, mnull, 4 * T, DM, DM);
        // 5) gate MLP layer 1 (+GELU) -> bufC = h bf16 [T][2048]
        gemm_bt<2><<<dim3(2 * DM / BN, T / BM), dim3(256), 0, stream>>>(
            bufA, Btg1, (void*)bufC, bg14, mnull, T, 2 * DM, 4 * DM);
        // 6) gate MLP layer 2 -> bufB = consensus f32 [T][1024]
        gemm_bt<3><<<dim3(DM / BN, T / BM), dim3(256), 0, stream>>>(
            bufC, Btg2, (void*)bufB, bg24, mnull, T, DM, 2 * DM);
        // 7) residual + LayerNorm -> out f32
        resid_ln<<<dim3(T), dim3(256), 0, stream>>>(
            (const float*)bufB, feat + (size_t)t0 * DM, lng, lnb,
            (float*)d_out + (size_t)t0 * DM);
    }
}

// Round 3
// 756.695 us; speedup vs baseline: 1.4432x; 1.4432x over previous
//
#include <hip/hip_runtime.h>
#include <cstdint>
#include <cstddef>

// ---------------- constants ----------------
#define DM   1024          // model dim
#define NT   8192          // B*L tokens
#define HD   256
#define BM 128
#define BN 128
#define BK 32

typedef __attribute__((ext_vector_type(4))) float f32x4;
typedef __attribute__((ext_vector_type(8))) short bf16x8;

__device__ __forceinline__ unsigned short f2bf(float f) {
    union { float f; uint32_t u; } v; v.f = f;
    return (unsigned short)((v.u + 0x7fffu + ((v.u >> 16) & 1u)) >> 16);
}
__device__ __forceinline__ float bf2f(unsigned short h) {
    union { uint32_t u; float f; } v; v.u = ((uint32_t)h) << 16;
    return v.f;
}

struct Ptr4 { const float* p[4]; };
struct Mask4 { const int* p[4]; };

// ---------------- prep kernels ----------------
__global__ void cvt_f32_to_bf16(const float* __restrict__ src,
                                unsigned short* __restrict__ dst, int n4) {
    int i = blockIdx.x * blockDim.x + threadIdx.x;
    if (i >= n4) return;
    float4 v = reinterpret_cast<const float4*>(src)[i];
    ushort4 o;
    o.x = f2bf(v.x); o.y = f2bf(v.y); o.z = f2bf(v.z); o.w = f2bf(v.w);
    reinterpret_cast<ushort4*>(dst)[i] = o;
}

// src fp32 [K][Nc] row-major  ->  dst bf16 [Nc][K] row-major (transposed)
__global__ void transpose_cvt(const float* __restrict__ src,
                              unsigned short* __restrict__ dst, int K, int Nc) {
    __shared__ float tile[32][33];
    const int n0 = blockIdx.x * 32, k0 = blockIdx.y * 32;
    const int tx = threadIdx.x & 31, ty = threadIdx.x >> 5;   // 32 x 8
#pragma unroll
    for (int i = 0; i < 4; ++i) {
        int k = ty + i * 8;
        tile[k][tx] = src[(size_t)(k0 + k) * Nc + n0 + tx];
    }
    __syncthreads();
#pragma unroll
    for (int i = 0; i < 4; ++i) {
        int n = ty + i * 8;
        dst[(size_t)(n0 + n) * K + k0 + tx] = f2bf(tile[tx][n]);
    }
}

// ---------------- GEMM: C[M][Nc] = A[M][K] x Bt[Nc][K]^T ----------------
// EPI: 0 = (acc+bias)*mask -> bf16   (masked modality projection)
//      1 = acc+bias        -> bf16
//      2 = gelu(acc+bias)  -> bf16   (exact erf GELU)
//      3 = acc+bias        -> f32
__device__ __forceinline__ void gload16(const void* g, void* l) {
    __builtin_amdgcn_global_load_lds(
        (const __attribute__((address_space(1))) void*)g,
        (__attribute__((address_space(3))) void*)l, 16, 0, 0);
}

template <int EPI>
__global__ void gemm_bt(const unsigned short* __restrict__ A,
                        const unsigned short* __restrict__ Bt,
                        void* __restrict__ out, Ptr4 bias, Mask4 masks,
                        int M, int Nc, int K) {
    __shared__ __attribute__((aligned(16))) unsigned short Als[BM * BK];
    __shared__ __attribute__((aligned(16))) unsigned short Bls[BN * BK];
    const int tid = threadIdx.x;
    const int wave = tid >> 6, lane = tid & 63;
    const int tileM = blockIdx.y * BM, tileN = blockIdx.x * BN;
    const int wr = wave >> 1, wc = wave & 1;

    f32x4 acc[4][4] = {};

    const int sr = tid >> 2;            // row within 64-row half
    const int sc = (tid & 3) * 8;       // k element offset
    const unsigned short* aSrc0 = A + (size_t)(tileM + sr) * K + sc;
    const unsigned short* aSrc1 = A + (size_t)(tileM + 64 + sr) * K + sc;
    const unsigned short* bSrc0 = Bt + (size_t)(tileN + sr) * K + sc;
    const unsigned short* bSrc1 = Bt + (size_t)(tileN + 64 + sr) * K + sc;
    unsigned short* aDst0 = &Als[wave * 512];
    unsigned short* aDst1 = &Als[2048 + wave * 512];
    unsigned short* bDst0 = &Bls[wave * 512];
    unsigned short* bDst1 = &Bls[2048 + wave * 512];

    const int la = lane & 15;
    const int lb = (lane >> 4) * 8;

    for (int k0 = 0; k0 < K; k0 += BK) {
        gload16(aSrc0 + k0, aDst0);
        gload16(aSrc1 + k0, aDst1);
        gload16(bSrc0 + k0, bDst0);
        gload16(bSrc1 + k0, bDst1);
        __syncthreads();
        bf16x8 af[4], bfr[4];
#pragma unroll
        for (int m = 0; m < 4; ++m)
            af[m] = *reinterpret_cast<const bf16x8*>(&Als[(wr * 64 + m * 16 + la) * BK + lb]);
#pragma unroll
        for (int n = 0; n < 4; ++n)
            bfr[n] = *reinterpret_cast<const bf16x8*>(&Bls[(wc * 64 + n * 16 + la) * BK + lb]);
#pragma unroll
        for (int m = 0; m < 4; ++m)
#pragma unroll
            for (int n = 0; n < 4; ++n)
                acc[m][n] = __builtin_amdgcn_mfma_f32_16x16x32_bf16(af[m], bfr[n], acc[m][n], 0, 0, 0);
        __syncthreads();
    }

    const float* bp = bias.p[tileN >> 10];
    const int rowT = tileM + wr * 64 + (lane >> 4) * 4;
    const int colT = tileN + wc * 64;
    unsigned short* outB = (unsigned short*)out;
    float* outF = (float*)out;

    float mv[4][4];
    if constexpr (EPI == 0) {
        const int* mp = masks.p[tileN >> 10];
#pragma unroll
        for (int m = 0; m < 4; ++m)
#pragma unroll
            for (int i = 0; i < 4; ++i)
                mv[m][i] = (float)mp[rowT + m * 16 + i];
    }

#pragma unroll
    for (int n = 0; n < 4; ++n) {
        const int gcol = colT + n * 16 + la;
        const float bv = bp[gcol & (DM - 1)];
#pragma unroll
        for (int m = 0; m < 4; ++m) {
#pragma unroll
            for (int i = 0; i < 4; ++i) {
                const int grow = rowT + m * 16 + i;
                float val = acc[m][n][i] + bv;
                if constexpr (EPI == 0) {
                    val *= mv[m][i];
                    outB[(size_t)grow * Nc + gcol] = f2bf(val);
                } else if constexpr (EPI == 1) {
                    outB[(size_t)grow * Nc + gcol] = f2bf(val);
                } else if constexpr (EPI == 2) {
                    val = 0.5f * val * (1.0f + erff(val * 0.70710678118654752f));
                    outB[(size_t)grow * Nc + gcol] = f2bf(val);
                } else {
                    outF[(size_t)grow * Nc + gcol] = val;
                }
            }
        }
    }
}

// ---------------- tiny 4-token attention ----------------
// qkv bf16 [T*4][3072] (q|k|v each 1024 cols); ctx bf16 [T*4][1024]
__global__ void attn4(const unsigned short* __restrict__ qkv,
                      unsigned short* __restrict__ ctx) {
    const int n = blockIdx.x;
    const int h = threadIdx.x >> 6;      // wave = head
    const int lane = threadIdx.x & 63;   // 4 elems per lane (hd=256)
    const size_t base = (size_t)n * 4 * 3072 + h * HD + lane * 4;

    float q[4][4], k[4][4], v[4][4];
#pragma unroll
    for (int m = 0; m < 4; ++m) {
        ushort4 uq = *reinterpret_cast<const ushort4*>(&qkv[base + (size_t)m * 3072]);
        ushort4 uk = *reinterpret_cast<const ushort4*>(&qkv[base + (size_t)m * 3072 + 1024]);
        ushort4 uv = *reinterpret_cast<const ushort4*>(&qkv[base + (size_t)m * 3072 + 2048]);
        q[m][0] = bf2f(uq.x); q[m][1] = bf2f(uq.y); q[m][2] = bf2f(uq.z); q[m][3] = bf2f(uq.w);
        k[m][0] = bf2f(uk.x); k[m][1] = bf2f(uk.y); k[m][2] = bf2f(uk.z); k[m][3] = bf2f(uk.w);
        v[m][0] = bf2f(uv.x); v[m][1] = bf2f(uv.y); v[m][2] = bf2f(uv.z); v[m][3] = bf2f(uv.w);
    }

    float s[4][4];
#pragma unroll
    for (int qi = 0; qi < 4; ++qi)
#pragma unroll
        for (int ki = 0; ki < 4; ++ki)
            s[qi][ki] = q[qi][0] * k[ki][0] + q[qi][1] * k[ki][1] +
                        q[qi][2] * k[ki][2] + q[qi][3] * k[ki][3];
#pragma unroll
    for (int off = 32; off >= 1; off >>= 1) {
#pragma unroll
        for (int qi = 0; qi < 4; ++qi)
#pragma unroll
            for (int ki = 0; ki < 4; ++ki)
                s[qi][ki] += __shfl_xor(s[qi][ki], off, 64);
    }

#pragma unroll
    for (int qi = 0; qi < 4; ++qi) {
        float s0 = s[qi][0] * 0.0625f, s1 = s[qi][1] * 0.0625f;
        float s2 = s[qi][2] * 0.0625f, s3 = s[qi][3] * 0.0625f;
        float mx = fmaxf(fmaxf(s0, s1), fmaxf(s2, s3));
        float e0 = __expf(s0 - mx), e1 = __expf(s1 - mx);
        float e2 = __expf(s2 - mx), e3 = __expf(s3 - mx);
        float inv = 1.0f / (e0 + e1 + e2 + e3);
        e0 *= inv; e1 *= inv; e2 *= inv; e3 *= inv;
        ushort4 o;
        o.x = f2bf(e0 * v[0][0] + e1 * v[1][0] + e2 * v[2][0] + e3 * v[3][0]);
        o.y = f2bf(e0 * v[0][1] + e1 * v[1][1] + e2 * v[2][1] + e3 * v[3][1]);
        o.z = f2bf(e0 * v[0][2] + e1 * v[1][2] + e2 * v[2][2] + e3 * v[3][2]);
        o.w = f2bf(e0 * v[0][3] + e1 * v[1][3] + e2 * v[2][3] + e3 * v[3][3]);
        *reinterpret_cast<ushort4*>(&ctx[(size_t)(n * 4 + qi) * 1024 + h * HD + lane * 4]) = o;
    }
}

// ---------------- residual + LayerNorm ----------------
__global__ void resid_ln(const float* __restrict__ cons, const float* __restrict__ feat,
                         const float* __restrict__ g, const float* __restrict__ b,
                         float* __restrict__ out) {
    const int row = blockIdx.x;
    const int t = threadIdx.x;          // 256 threads x 4 floats
    const size_t base = (size_t)row * DM + t * 4;
    float4 c = *reinterpret_cast<const float4*>(&cons[base]);
    float4 f = *reinterpret_cast<const float4*>(&feat[base]);
    float y0 = c.x + f.x, y1 = c.y + f.y, y2 = c.z + f.z, y3 = c.w + f.w;
    float sum = y0 + y1 + y2 + y3;
    float sq = y0 * y0 + y1 * y1 + y2 * y2 + y3 * y3;
#pragma unroll
    for (int off = 32; off >= 1; off >>= 1) {
        sum += __shfl_xor(sum, off, 64);
        sq += __shfl_xor(sq, off, 64);
    }
    __shared__ float rs[4], rq[4];
    const int wv = t >> 6, ln = t & 63;
    if (ln == 0) { rs[wv] = sum; rq[wv] = sq; }
    __syncthreads();
    sum = rs[0] + rs[1] + rs[2] + rs[3];
    sq = rq[0] + rq[1] + rq[2] + rq[3];
    const float mu = sum * (1.0f / DM);
    const float var = sq * (1.0f / DM) - mu * mu;
    const float rstd = rsqrtf(var + 1e-5f);
    float4 gg = *reinterpret_cast<const float4*>(&g[t * 4]);
    float4 bb = *reinterpret_cast<const float4*>(&b[t * 4]);
    float4 o;
    o.x = (y0 - mu) * rstd * gg.x + bb.x;
    o.y = (y1 - mu) * rstd * gg.y + bb.y;
    o.z = (y2 - mu) * rstd * gg.z + bb.z;
    o.w = (y3 - mu) * rstd * gg.w + bb.w;
    *reinterpret_cast<float4*>(&out[base]) = o;
}

// ---------------- launch ----------------
extern "C" void kernel_launch(void* const* d_in, const int* in_sizes, int n_in,
                              void* d_out, int out_size, void* d_ws, size_t ws_size,
                              hipStream_t stream) {
    (void)in_sizes; (void)n_in; (void)out_size;
    const float* feat = (const float*)d_in[0];
    const int* am = (const int*)d_in[1];
    const int* dmk = (const int*)d_in[2];
    const int* em = (const int*)d_in[3];
    const int* hmk = (const int*)d_in[4];
    const float* Wa = (const float*)d_in[5];  const float* ba = (const float*)d_in[6];
    const float* Wd = (const float*)d_in[7];  const float* bd = (const float*)d_in[8];
    const float* We = (const float*)d_in[9];  const float* be = (const float*)d_in[10];
    const float* Wh = (const float*)d_in[11]; const float* bh = (const float*)d_in[12];
    const float* Wq = (const float*)d_in[13]; const float* bq = (const float*)d_in[14];
    const float* Wk = (const float*)d_in[15]; const float* bk = (const float*)d_in[16];
    const float* Wv = (const float*)d_in[17]; const float* bv = (const float*)d_in[18];
    const float* Wo = (const float*)d_in[19]; const float* bo = (const float*)d_in[20];
    const float* Wg1 = (const float*)d_in[21]; const float* bg1 = (const float*)d_in[22];
    const float* Wg2 = (const float*)d_in[23]; const float* bg2 = (const float*)d_in[24];
    const float* lng = (const float*)d_in[25]; const float* lnb = (const float*)d_in[26];

    char* ws = (char*)d_ws;
    size_t off = 0;
    auto take = [&](size_t bytes) -> char* {
        char* r = ws + off;
        off = (off + bytes + 255) & ~(size_t)255;
        return r;
    };
    // ---- fixed weight/feature allocations: ~54.6 MB ----
    unsigned short* featB = (unsigned short*)take((size_t)NT * DM * 2);
    unsigned short* Bt1   = (unsigned short*)take((size_t)4 * DM * DM * 2);
    unsigned short* Btqkv = (unsigned short*)take((size_t)3 * DM * DM * 2);
    unsigned short* Bto   = (unsigned short*)take((size_t)DM * DM * 2);
    unsigned short* Btg1  = (unsigned short*)take((size_t)2 * DM * 4 * DM * 2);
    unsigned short* Btg2  = (unsigned short*)take((size_t)DM * 2 * DM * 2);
    const size_t fixed = off;

    // --- prep: convert features, transpose+convert weights to bf16 [N][K] ---
    cvt_f32_to_bf16<<<dim3((NT * DM / 4 + 255) / 256), dim3(256), 0, stream>>>(
        feat, featB, NT * DM / 4);
    auto tl = [&](const float* src, unsigned short* dst, int K, int Nc) {
        transpose_cvt<<<dim3(Nc / 32, K / 32), dim3(256), 0, stream>>>(src, dst, K, Nc);
    };
    tl(Wa, Bt1, DM, DM);
    tl(Wd, Bt1 + (size_t)DM * DM, DM, DM);
    tl(We, Bt1 + (size_t)2 * DM * DM, DM, DM);
    tl(Wh, Bt1 + (size_t)3 * DM * DM, DM, DM);
    tl(Wq, Btqkv, DM, DM);
    tl(Wk, Btqkv + (size_t)DM * DM, DM, DM);
    tl(Wv, Btqkv + (size_t)2 * DM * DM, DM, DM);
    tl(Wo, Bto, DM, DM);
    tl(Wg1, Btg1, 4 * DM, 2 * DM);
    tl(Wg2, Btg2, 2 * DM, DM);

    Ptr4 b1{{ba, bd, be, bh}};
    Ptr4 bqkv{{bq, bk, bv, nullptr}};
    Ptr4 bo4{{bo, nullptr, nullptr, nullptr}};
    Ptr4 bg14{{bg1, bg1 + DM, nullptr, nullptr}};
    Ptr4 bg24{{bg2, nullptr, nullptr, nullptr}};
    Mask4 mnull{{nullptr, nullptr, nullptr, nullptr}};
    Mask4 mkAll{{am, dmk, em, hmk}};

    // ---- plan B: full-size GEMMs, chunk only the attention path ----
    // regX (67.1MB): x -> attended -> consensus(f32)
    // regH (>=34MB): {qkv_c, ctx_c} during attention phase, then h
    const size_t xBytes = (size_t)NT * 4096 * 2;
    const size_t hBytes = (size_t)NT * 2048 * 2 + 512;
    int T2 = 0;
    {
        const int cands[4] = {8192, 4096, 2048, 1024};
        for (int ci = 0; ci < 4; ++ci) {
            int c = cands[ci];
            size_t chunkB = (size_t)c * 24576 + 512 + (size_t)c * 8192;
            size_t regHB = chunkB > hBytes ? chunkB : hBytes;
            if (fixed + xBytes + 256 + regHB + 4096 <= ws_size) { T2 = c; break; }
        }
    }

    if (T2 > 0) {
        char* regX = take(xBytes);
        size_t chunkB = (size_t)T2 * 24576 + 512 + (size_t)T2 * 8192;
        char* regH = take(chunkB > hBytes ? chunkB : hBytes);
        unsigned short* x = (unsigned short*)regX;      // x / attended (bf16)
        float* cons = (float*)regX;                     // consensus (f32)
        unsigned short* h = (unsigned short*)regH;
        unsigned short* qkv_c = (unsigned short*)regH;
        unsigned short* ctx_c = (unsigned short*)(regH + (size_t)T2 * 24576 + 512);

        // 1) masked modality projections, full: x[NT][4096]
        gemm_bt<0><<<dim3(32, NT / BM), dim3(256), 0, stream>>>(
            featB, Bt1, (void*)x, b1, mkAll, NT, 4 * DM, DM);
        // 2-4) attention path, chunked over tokens
        for (int t0 = 0; t0 < NT; t0 += T2) {
            unsigned short* xc = x + (size_t)t0 * 4096;
            gemm_bt<1><<<dim3(24, 4 * T2 / BM), dim3(256), 0, stream>>>(
                xc, Btqkv, (void*)qkv_c, bqkv, mnull, 4 * T2, 3 * DM, DM);
            attn4<<<dim3(T2), dim3(256), 0, stream>>>(qkv_c, ctx_c);
            gemm_bt<1><<<dim3(8, 4 * T2 / BM), dim3(256), 0, stream>>>(
                ctx_c, Bto, (void*)xc, bo4, mnull, 4 * T2, DM, DM);
        }
        // 5) gate MLP layer 1 (+GELU), full: h[NT][2048]
        gemm_bt<2><<<dim3(16, NT / BM), dim3(256), 0, stream>>>(
            x, Btg1, (void*)h, bg14, mnull, NT, 2 * DM, 4 * DM);
        // 6) gate MLP layer 2, full: cons f32 [NT][1024] (overwrites regX head)
        gemm_bt<3><<<dim3(8, NT / BM), dim3(256), 0, stream>>>(
            h, Btg2, (void*)cons, bg24, mnull, NT, DM, 2 * DM);
        // 7) residual + LayerNorm
        resid_ln<<<dim3(NT), dim3(256), 0, stream>>>(cons, feat, lng, lnb, (float*)d_out);
        return;
    }

    // ---- plan A fallback (known-good fully-chunked pipeline) ----
    const size_t avail = (ws_size > fixed) ? (ws_size - fixed) : 0;
    int T = 2048;
    while (T > 128 && ((size_t)T * 40960 + 4096) > avail) T >>= 1;
    unsigned short* bufA = (unsigned short*)take((size_t)T * 4096 * 2);
    unsigned short* bufB = (unsigned short*)take((size_t)T * 4 * 3072 * 2);
    unsigned short* bufC = (unsigned short*)take((size_t)T * 4 * 1024 * 2);

    const int nch = NT / T;
    for (int c = 0; c < nch; ++c) {
        const int t0 = c * T;
        Mask4 mk{{am + t0, dmk + t0, em + t0, hmk + t0}};
        gemm_bt<0><<<dim3(4 * DM / BN, T / BM), dim3(256), 0, stream>>>(
            featB + (size_t)t0 * DM, Bt1, (void*)bufA, b1, mk, T, 4 * DM, DM);
        gemm_bt<1><<<dim3(3 * DM / BN, 4 * T / BM), dim3(256), 0, stream>>>(
            bufA, Btqkv, (void*)bufB, bqkv, mnull, 4 * T, 3 * DM, DM);
        attn4<<<dim3(T), dim3(256), 0, stream>>>(bufB, bufC);
        gemm_bt<1><<<dim3(DM / BN, 4 * T / BM), dim3(256), 0, stream>>>(
            bufC, Bto, (void*)bufA, bo4, mnull, 4 * T, DM, DM);
        gemm_bt<2><<<dim3(2 * DM / BN, T / BM), dim3(256), 0, stream>>>(
            bufA, Btg1, (void*)bufC, bg14, mnull, T, 2 * DM, 4 * DM);
        gemm_bt<3><<<dim3(DM / BN, T / BM), dim3(256), 0, stream>>>(
            bufC, Btg2, (void*)bufB, bg24, mnull, T, DM, 2 * DM);
        resid_ln<<<dim3(T), dim3(256), 0, stream>>>(
            (const float*)bufB, feat + (size_t)t0 * DM, lng, lnb,
            (float*)d_out + (size_t)t0 * DM);
    }
}

// Round 4
// 725.157 us; speedup vs baseline: 1.5060x; 1.0435x over previous
//
#include <hip/hip_runtime.h>
#include <cstdint>
#include <cstddef>

// ---------------- constants ----------------
#define DM   1024          // model dim
#define NT   8192          // B*L tokens
#define HD   256
#define BM 128
#define BN 128
#define BK 32

typedef __attribute__((ext_vector_type(4))) float f32x4;
typedef __attribute__((ext_vector_type(8))) short bf16x8;

#define MF(a_, b_, c_) __builtin_amdgcn_mfma_f32_16x16x32_bf16(a_, b_, c_, 0, 0, 0)

__device__ __forceinline__ unsigned short f2bf(float f) {
    union { float f; uint32_t u; } v; v.f = f;
    return (unsigned short)((v.u + 0x7fffu + ((v.u >> 16) & 1u)) >> 16);
}
__device__ __forceinline__ float bf2f(unsigned short h) {
    union { uint32_t u; float f; } v; v.u = ((uint32_t)h) << 16;
    return v.f;
}

struct Ptr4 { const float* p[4]; };
struct Mask4 { const int* p[4]; };

// ---------------- prep kernels ----------------
__global__ void cvt_f32_to_bf16(const float* __restrict__ src,
                                unsigned short* __restrict__ dst, int n4) {
    int i = blockIdx.x * blockDim.x + threadIdx.x;
    if (i >= n4) return;
    float4 v = reinterpret_cast<const float4*>(src)[i];
    ushort4 o;
    o.x = f2bf(v.x); o.y = f2bf(v.y); o.z = f2bf(v.z); o.w = f2bf(v.w);
    reinterpret_cast<ushort4*>(dst)[i] = o;
}

// src fp32 [K][Nc] row-major  ->  dst bf16 [Nc][K] row-major (transposed)
__global__ void transpose_cvt(const float* __restrict__ src,
                              unsigned short* __restrict__ dst, int K, int Nc) {
    __shared__ float tile[32][33];
    const int n0 = blockIdx.x * 32, k0 = blockIdx.y * 32;
    const int tx = threadIdx.x & 31, ty = threadIdx.x >> 5;   // 32 x 8
#pragma unroll
    for (int i = 0; i < 4; ++i) {
        int k = ty + i * 8;
        tile[k][tx] = src[(size_t)(k0 + k) * Nc + n0 + tx];
    }
    __syncthreads();
#pragma unroll
    for (int i = 0; i < 4; ++i) {
        int n = ty + i * 8;
        dst[(size_t)(n0 + n) * K + k0 + tx] = f2bf(tile[tx][n]);
    }
}

__device__ __forceinline__ void gload16(const void* g, void* l) {
    __builtin_amdgcn_global_load_lds(
        (const __attribute__((address_space(1))) void*)g,
        (__attribute__((address_space(3))) void*)l, 16, 0, 0);
}

// ---------------- 128x128 GEMM (legacy, small grids / fallback) ----------------
// EPI: 0=(acc+bias)*mask->bf16  1=acc+bias->bf16  2=gelu->bf16  3=acc+bias->f32
template <int EPI>
__global__ void gemm_bt(const unsigned short* __restrict__ A,
                        const unsigned short* __restrict__ Bt,
                        void* __restrict__ out, Ptr4 bias, Mask4 masks,
                        int M, int Nc, int K) {
    __shared__ __attribute__((aligned(16))) unsigned short Als[BM * BK];
    __shared__ __attribute__((aligned(16))) unsigned short Bls[BN * BK];
    const int tid = threadIdx.x;
    const int wave = tid >> 6, lane = tid & 63;
    const int tileM = blockIdx.y * BM, tileN = blockIdx.x * BN;
    const int wr = wave >> 1, wc = wave & 1;

    f32x4 acc[4][4] = {};

    const int sr = tid >> 2;
    const int sc = (tid & 3) * 8;
    const unsigned short* aSrc0 = A + (size_t)(tileM + sr) * K + sc;
    const unsigned short* aSrc1 = A + (size_t)(tileM + 64 + sr) * K + sc;
    const unsigned short* bSrc0 = Bt + (size_t)(tileN + sr) * K + sc;
    const unsigned short* bSrc1 = Bt + (size_t)(tileN + 64 + sr) * K + sc;
    unsigned short* aDst0 = &Als[wave * 512];
    unsigned short* aDst1 = &Als[2048 + wave * 512];
    unsigned short* bDst0 = &Bls[wave * 512];
    unsigned short* bDst1 = &Bls[2048 + wave * 512];

    const int la = lane & 15;
    const int lb = (lane >> 4) * 8;

    for (int k0 = 0; k0 < K; k0 += BK) {
        gload16(aSrc0 + k0, aDst0);
        gload16(aSrc1 + k0, aDst1);
        gload16(bSrc0 + k0, bDst0);
        gload16(bSrc1 + k0, bDst1);
        __syncthreads();
        bf16x8 af[4], bfr[4];
#pragma unroll
        for (int m = 0; m < 4; ++m)
            af[m] = *reinterpret_cast<const bf16x8*>(&Als[(wr * 64 + m * 16 + la) * BK + lb]);
#pragma unroll
        for (int n = 0; n < 4; ++n)
            bfr[n] = *reinterpret_cast<const bf16x8*>(&Bls[(wc * 64 + n * 16 + la) * BK + lb]);
#pragma unroll
        for (int m = 0; m < 4; ++m)
#pragma unroll
            for (int n = 0; n < 4; ++n)
                acc[m][n] = MF(af[m], bfr[n], acc[m][n]);
        __syncthreads();
    }

    const float* bp = bias.p[tileN >> 10];
    const int rowT = tileM + wr * 64 + (lane >> 4) * 4;
    const int colT = tileN + wc * 64;
    unsigned short* outB = (unsigned short*)out;
    float* outF = (float*)out;

    float mv[4][4];
    if constexpr (EPI == 0) {
        const int* mp = masks.p[tileN >> 10];
#pragma unroll
        for (int m = 0; m < 4; ++m)
#pragma unroll
            for (int i = 0; i < 4; ++i)
                mv[m][i] = (float)mp[rowT + m * 16 + i];
    }

#pragma unroll
    for (int n = 0; n < 4; ++n) {
        const int gcol = colT + n * 16 + la;
        const float bv = bp[gcol & (DM - 1)];
#pragma unroll
        for (int m = 0; m < 4; ++m) {
#pragma unroll
            for (int i = 0; i < 4; ++i) {
                const int grow = rowT + m * 16 + i;
                float val = acc[m][n][i] + bv;
                if constexpr (EPI == 0) {
                    val *= mv[m][i];
                    outB[(size_t)grow * Nc + gcol] = f2bf(val);
                } else if constexpr (EPI == 1) {
                    outB[(size_t)grow * Nc + gcol] = f2bf(val);
                } else if constexpr (EPI == 2) {
                    val = 0.5f * val * (1.0f + erff(val * 0.70710678118654752f));
                    outB[(size_t)grow * Nc + gcol] = f2bf(val);
                } else {
                    outF[(size_t)grow * Nc + gcol] = val;
                }
            }
        }
    }
}

// ---------------- 256x256 8-phase GEMM (T2+T3+T4+T5) ----------------
// BM=BN=256, BK=64, 8 waves (2Mx4N), per-wave 128x64, dbuf LDS 128KB (dynamic).
// st_16x32 swizzle: LDS linear dest; source pre-XOR'd; read XOR'd (rule 21).
// Counted vmcnt(2) gate once per K-tile; raw s_barrier (no vmcnt drain).
template <int EPI>
__global__ __launch_bounds__(512, 2)
void gemm_bt8(const unsigned short* __restrict__ A,
              const unsigned short* __restrict__ Bt,
              void* __restrict__ out, Ptr4 bias, Mask4 masks,
              int M, int Nc, int K) {
    extern __shared__ __attribute__((aligned(16))) unsigned short smem[];
    unsigned short* Asm = smem;            // [2][256*64]
    unsigned short* Bsm = smem + 32768;    // [2][256*64]
    const int tid = threadIdx.x;
    const int wave = tid >> 6, lane = tid & 63;
    const int wr = wave >> 2, wc = wave & 3;
    const int tileM = blockIdx.y * 256, tileN = blockIdx.x * 256;
    const int la = lane & 15, lh = lane >> 4;

    f32x4 acc[8][4] = {};

    // staging: thread covers row (tid>>3) within a 64-row group, chunk (tid&7)*16B
    const int srow = tid >> 3;
    const int scol = (tid & 7) * 16;
    const int sswz = (scol ^ ((srow & 7) << 4)) >> 1;   // pre-swizzled source elem off
    const unsigned short* aS = A + (size_t)(tileM + srow) * K + sswz;
    const unsigned short* bS = Bt + (size_t)(tileN + srow) * K + sswz;
    // swizzled LDS read elem offsets within a 64-elem (128B) row
    const int ra0 = (((lh * 16)) ^ ((la & 7) << 4)) >> 1;        // ks=0
    const int ra1 = ((64 + lh * 16) ^ ((la & 7) << 4)) >> 1;     // ks=1

    const int NKT = K >> 6;

#define STG_A(BUF, H, KO) do { \
    gload16(aS + (size_t)((H) * 128) * K + (KO), Asm + (BUF) * 16384 + ((H) * 128) * 64 + wave * 512); \
    gload16(aS + (size_t)((H) * 128 + 64) * K + (KO), Asm + (BUF) * 16384 + ((H) * 128 + 64) * 64 + wave * 512); \
} while (0)
#define STG_B(BUF, H, KO) do { \
    gload16(bS + (size_t)((H) * 128) * K + (KO), Bsm + (BUF) * 16384 + ((H) * 128) * 64 + wave * 512); \
    gload16(bS + (size_t)((H) * 128 + 64) * K + (KO), Bsm + (BUF) * 16384 + ((H) * 128 + 64) * 64 + wave * 512); \
} while (0)

    // prologue: stage K-tile 0 into buf 0 (8 loads)
    STG_A(0, 0, 0); STG_A(0, 1, 0); STG_B(0, 0, 0); STG_B(0, 1, 0);

    int buf = 0;
    for (int kt = 0; kt < NKT; ++kt) {
        const size_t ko = (size_t)((kt + 1 < NKT) ? (kt + 1) : kt) * 64;  // clamped prefetch
        const int nb = buf ^ 1;
        const unsigned short* Ac = Asm + buf * 16384;
        const unsigned short* Bc = Bsm + buf * 16384;
        bf16x8 aR[8], bR[8];

        // ---- phase 1: stage A-h0(next); gate tile kt; read A[m0-3],B[n0-1]; MFMA q00 ----
        STG_A(nb, 0, ko);
        asm volatile("s_waitcnt vmcnt(2)" ::: "memory");
        __builtin_amdgcn_s_barrier();
        asm volatile("" ::: "memory");
#pragma unroll
        for (int m = 0; m < 4; ++m) {
            aR[m * 2 + 0] = *reinterpret_cast<const bf16x8*>(&Ac[(wr * 128 + m * 16 + la) * 64 + ra0]);
            aR[m * 2 + 1] = *reinterpret_cast<const bf16x8*>(&Ac[(wr * 128 + m * 16 + la) * 64 + ra1]);
        }
#pragma unroll
        for (int n = 0; n < 2; ++n) {
            bR[n * 2 + 0] = *reinterpret_cast<const bf16x8*>(&Bc[(wc * 64 + n * 16 + la) * 64 + ra0]);
            bR[n * 2 + 1] = *reinterpret_cast<const bf16x8*>(&Bc[(wc * 64 + n * 16 + la) * 64 + ra1]);
        }
        __builtin_amdgcn_s_barrier();
        __builtin_amdgcn_s_setprio(1);
#pragma unroll
        for (int m = 0; m < 4; ++m)
#pragma unroll
            for (int n = 0; n < 2; ++n) {
                acc[m][n] = MF(aR[m * 2 + 0], bR[n * 2 + 0], acc[m][n]);
                acc[m][n] = MF(aR[m * 2 + 1], bR[n * 2 + 1], acc[m][n]);
            }
        __builtin_amdgcn_s_setprio(0);

        // ---- phase 2: read B[n2-3]; stage A-h1(next); MFMA q01 ----
#pragma unroll
        for (int n = 2; n < 4; ++n) {
            bR[n * 2 + 0] = *reinterpret_cast<const bf16x8*>(&Bc[(wc * 64 + n * 16 + la) * 64 + ra0]);
            bR[n * 2 + 1] = *reinterpret_cast<const bf16x8*>(&Bc[(wc * 64 + n * 16 + la) * 64 + ra1]);
        }
        STG_A(nb, 1, ko);
        __builtin_amdgcn_s_barrier();
        __builtin_amdgcn_s_setprio(1);
#pragma unroll
        for (int m = 0; m < 4; ++m)
#pragma unroll
            for (int n = 2; n < 4; ++n) {
                acc[m][n] = MF(aR[m * 2 + 0], bR[n * 2 + 0], acc[m][n]);
                acc[m][n] = MF(aR[m * 2 + 1], bR[n * 2 + 1], acc[m][n]);
            }
        __builtin_amdgcn_s_setprio(0);

        // ---- phase 3: read A[m4-7]; stage B-h0(next); MFMA q10 ----
#pragma unroll
        for (int m = 0; m < 4; ++m) {
            aR[m * 2 + 0] = *reinterpret_cast<const bf16x8*>(&Ac[(wr * 128 + (m + 4) * 16 + la) * 64 + ra0]);
            aR[m * 2 + 1] = *reinterpret_cast<const bf16x8*>(&Ac[(wr * 128 + (m + 4) * 16 + la) * 64 + ra1]);
        }
        STG_B(nb, 0, ko);
        __builtin_amdgcn_s_barrier();
        __builtin_amdgcn_s_setprio(1);
#pragma unroll
        for (int m = 0; m < 4; ++m)
#pragma unroll
            for (int n = 0; n < 2; ++n) {
                acc[m + 4][n] = MF(aR[m * 2 + 0], bR[n * 2 + 0], acc[m + 4][n]);
                acc[m + 4][n] = MF(aR[m * 2 + 1], bR[n * 2 + 1], acc[m + 4][n]);
            }
        __builtin_amdgcn_s_setprio(0);

        // ---- phase 4: stage B-h1(next); MFMA q11; end-tile barrier ----
        STG_B(nb, 1, ko);
        __builtin_amdgcn_s_barrier();
        __builtin_amdgcn_s_setprio(1);
#pragma unroll
        for (int m = 0; m < 4; ++m)
#pragma unroll
            for (int n = 2; n < 4; ++n) {
                acc[m + 4][n] = MF(aR[m * 2 + 0], bR[n * 2 + 0], acc[m + 4][n]);
                acc[m + 4][n] = MF(aR[m * 2 + 1], bR[n * 2 + 1], acc[m + 4][n]);
            }
        __builtin_amdgcn_s_setprio(0);
        asm volatile("" ::: "memory");
        __builtin_amdgcn_s_barrier();
        buf = nb;
    }
#undef STG_A
#undef STG_B

    // ---- epilogue ----
    const float* bp = bias.p[tileN >> 10];
    unsigned short* outB = (unsigned short*)out;
    float* outF = (float*)out;
    const int* mp = (EPI == 0) ? masks.p[tileN >> 10] : nullptr;

#pragma unroll
    for (int n = 0; n < 4; ++n) {
        const int gcol = tileN + wc * 64 + n * 16 + la;
        const float bv = bp[gcol & (DM - 1)];
#pragma unroll
        for (int m = 0; m < 8; ++m) {
#pragma unroll
            for (int i = 0; i < 4; ++i) {
                const int grow = tileM + wr * 128 + m * 16 + lh * 4 + i;
                float val = acc[m][n][i] + bv;
                if constexpr (EPI == 0) {
                    val *= (float)mp[grow];
                    outB[(size_t)grow * Nc + gcol] = f2bf(val);
                } else if constexpr (EPI == 1) {
                    outB[(size_t)grow * Nc + gcol] = f2bf(val);
                } else if constexpr (EPI == 2) {
                    val = 0.5f * val * (1.0f + erff(val * 0.70710678118654752f));
                    outB[(size_t)grow * Nc + gcol] = f2bf(val);
                } else {
                    outF[(size_t)grow * Nc + gcol] = val;
                }
            }
        }
    }
}

// ---------------- tiny 4-token attention ----------------
__global__ void attn4(const unsigned short* __restrict__ qkv,
                      unsigned short* __restrict__ ctx) {
    const int n = blockIdx.x;
    const int h = threadIdx.x >> 6;
    const int lane = threadIdx.x & 63;
    const size_t base = (size_t)n * 4 * 3072 + h * HD + lane * 4;

    float q[4][4], k[4][4], v[4][4];
#pragma unroll
    for (int m = 0; m < 4; ++m) {
        ushort4 uq = *reinterpret_cast<const ushort4*>(&qkv[base + (size_t)m * 3072]);
        ushort4 uk = *reinterpret_cast<const ushort4*>(&qkv[base + (size_t)m * 3072 + 1024]);
        ushort4 uv = *reinterpret_cast<const ushort4*>(&qkv[base + (size_t)m * 3072 + 2048]);
        q[m][0] = bf2f(uq.x); q[m][1] = bf2f(uq.y); q[m][2] = bf2f(uq.z); q[m][3] = bf2f(uq.w);
        k[m][0] = bf2f(uk.x); k[m][1] = bf2f(uk.y); k[m][2] = bf2f(uk.z); k[m][3] = bf2f(uk.w);
        v[m][0] = bf2f(uv.x); v[m][1] = bf2f(uv.y); v[m][2] = bf2f(uv.z); v[m][3] = bf2f(uv.w);
    }

    float s[4][4];
#pragma unroll
    for (int qi = 0; qi < 4; ++qi)
#pragma unroll
        for (int ki = 0; ki < 4; ++ki)
            s[qi][ki] = q[qi][0] * k[ki][0] + q[qi][1] * k[ki][1] +
                        q[qi][2] * k[ki][2] + q[qi][3] * k[ki][3];
#pragma unroll
    for (int off = 32; off >= 1; off >>= 1) {
#pragma unroll
        for (int qi = 0; qi < 4; ++qi)
#pragma unroll
            for (int ki = 0; ki < 4; ++ki)
                s[qi][ki] += __shfl_xor(s[qi][ki], off, 64);
    }

#pragma unroll
    for (int qi = 0; qi < 4; ++qi) {
        float s0 = s[qi][0] * 0.0625f, s1 = s[qi][1] * 0.0625f;
        float s2 = s[qi][2] * 0.0625f, s3 = s[qi][3] * 0.0625f;
        float mx = fmaxf(fmaxf(s0, s1), fmaxf(s2, s3));
        float e0 = __expf(s0 - mx), e1 = __expf(s1 - mx);
        float e2 = __expf(s2 - mx), e3 = __expf(s3 - mx);
        float inv = 1.0f / (e0 + e1 + e2 + e3);
        e0 *= inv; e1 *= inv; e2 *= inv; e3 *= inv;
        ushort4 o;
        o.x = f2bf(e0 * v[0][0] + e1 * v[1][0] + e2 * v[2][0] + e3 * v[3][0]);
        o.y = f2bf(e0 * v[0][1] + e1 * v[1][1] + e2 * v[2][1] + e3 * v[3][1]);
        o.z = f2bf(e0 * v[0][2] + e1 * v[1][2] + e2 * v[2][2] + e3 * v[3][2]);
        o.w = f2bf(e0 * v[0][3] + e1 * v[1][3] + e2 * v[2][3] + e3 * v[3][3]);
        *reinterpret_cast<ushort4*>(&ctx[(size_t)(n * 4 + qi) * 1024 + h * HD + lane * 4]) = o;
    }
}

// ---------------- residual + LayerNorm ----------------
__global__ void resid_ln(const float* __restrict__ cons, const float* __restrict__ feat,
                         const float* __restrict__ g, const float* __restrict__ b,
                         float* __restrict__ out) {
    const int row = blockIdx.x;
    const int t = threadIdx.x;
    const size_t base = (size_t)row * DM + t * 4;
    float4 c = *reinterpret_cast<const float4*>(&cons[base]);
    float4 f = *reinterpret_cast<const float4*>(&feat[base]);
    float y0 = c.x + f.x, y1 = c.y + f.y, y2 = c.z + f.z, y3 = c.w + f.w;
    float sum = y0 + y1 + y2 + y3;
    float sq = y0 * y0 + y1 * y1 + y2 * y2 + y3 * y3;
#pragma unroll
    for (int off = 32; off >= 1; off >>= 1) {
        sum += __shfl_xor(sum, off, 64);
        sq += __shfl_xor(sq, off, 64);
    }
    __shared__ float rs[4], rq[4];
    const int wv = t >> 6, ln = t & 63;
    if (ln == 0) { rs[wv] = sum; rq[wv] = sq; }
    __syncthreads();
    sum = rs[0] + rs[1] + rs[2] + rs[3];
    sq = rq[0] + rq[1] + rq[2] + rq[3];
    const float mu = sum * (1.0f / DM);
    const float var = sq * (1.0f / DM) - mu * mu;
    const float rstd = rsqrtf(var + 1e-5f);
    float4 gg = *reinterpret_cast<const float4*>(&g[t * 4]);
    float4 bb = *reinterpret_cast<const float4*>(&b[t * 4]);
    float4 o;
    o.x = (y0 - mu) * rstd * gg.x + bb.x;
    o.y = (y1 - mu) * rstd * gg.y + bb.y;
    o.z = (y2 - mu) * rstd * gg.z + bb.z;
    o.w = (y3 - mu) * rstd * gg.w + bb.w;
    *reinterpret_cast<float4*>(&out[base]) = o;
}

// ---------------- launch ----------------
extern "C" void kernel_launch(void* const* d_in, const int* in_sizes, int n_in,
                              void* d_out, int out_size, void* d_ws, size_t ws_size,
                              hipStream_t stream) {
    (void)in_sizes; (void)n_in; (void)out_size;
    const float* feat = (const float*)d_in[0];
    const int* am = (const int*)d_in[1];
    const int* dmk = (const int*)d_in[2];
    const int* em = (const int*)d_in[3];
    const int* hmk = (const int*)d_in[4];
    const float* Wa = (const float*)d_in[5];  const float* ba = (const float*)d_in[6];
    const float* Wd = (const float*)d_in[7];  const float* bd = (const float*)d_in[8];
    const float* We = (const float*)d_in[9];  const float* be = (const float*)d_in[10];
    const float* Wh = (const float*)d_in[11]; const float* bh = (const float*)d_in[12];
    const float* Wq = (const float*)d_in[13]; const float* bq = (const float*)d_in[14];
    const float* Wk = (const float*)d_in[15]; const float* bk = (const float*)d_in[16];
    const float* Wv = (const float*)d_in[17]; const float* bv = (const float*)d_in[18];
    const float* Wo = (const float*)d_in[19]; const float* bo = (const float*)d_in[20];
    const float* Wg1 = (const float*)d_in[21]; const float* bg1 = (const float*)d_in[22];
    const float* Wg2 = (const float*)d_in[23]; const float* bg2 = (const float*)d_in[24];
    const float* lng = (const float*)d_in[25]; const float* lnb = (const float*)d_in[26];

    // opt-in to 128KB dynamic LDS for the 8-phase kernels (idempotent, capture-safe)
    hipFuncSetAttribute(reinterpret_cast<const void*>(&gemm_bt8<0>),
                        hipFuncAttributeMaxDynamicSharedMemorySize, 131072);
    hipFuncSetAttribute(reinterpret_cast<const void*>(&gemm_bt8<1>),
                        hipFuncAttributeMaxDynamicSharedMemorySize, 131072);
    hipFuncSetAttribute(reinterpret_cast<const void*>(&gemm_bt8<2>),
                        hipFuncAttributeMaxDynamicSharedMemorySize, 131072);

    char* ws = (char*)d_ws;
    size_t off = 0;
    auto take = [&](size_t bytes) -> char* {
        char* r = ws + off;
        off = (off + bytes + 255) & ~(size_t)255;
        return r;
    };
    // ---- fixed weight/feature allocations: ~54.6 MB ----
    unsigned short* featB = (unsigned short*)take((size_t)NT * DM * 2);
    unsigned short* Bt1   = (unsigned short*)take((size_t)4 * DM * DM * 2);
    unsigned short* Btqkv = (unsigned short*)take((size_t)3 * DM * DM * 2);
    unsigned short* Bto   = (unsigned short*)take((size_t)DM * DM * 2);
    unsigned short* Btg1  = (unsigned short*)take((size_t)2 * DM * 4 * DM * 2);
    unsigned short* Btg2  = (unsigned short*)take((size_t)DM * 2 * DM * 2);
    const size_t fixed = off;

    cvt_f32_to_bf16<<<dim3((NT * DM / 4 + 255) / 256), dim3(256), 0, stream>>>(
        feat, featB, NT * DM / 4);
    auto tl = [&](const float* src, unsigned short* dst, int K, int Nc) {
        transpose_cvt<<<dim3(Nc / 32, K / 32), dim3(256), 0, stream>>>(src, dst, K, Nc);
    };
    tl(Wa, Bt1, DM, DM);
    tl(Wd, Bt1 + (size_t)DM * DM, DM, DM);
    tl(We, Bt1 + (size_t)2 * DM * DM, DM, DM);
    tl(Wh, Bt1 + (size_t)3 * DM * DM, DM, DM);
    tl(Wq, Btqkv, DM, DM);
    tl(Wk, Btqkv + (size_t)DM * DM, DM, DM);
    tl(Wv, Btqkv + (size_t)2 * DM * DM, DM, DM);
    tl(Wo, Bto, DM, DM);
    tl(Wg1, Btg1, 4 * DM, 2 * DM);
    tl(Wg2, Btg2, 2 * DM, DM);

    Ptr4 b1{{ba, bd, be, bh}};
    Ptr4 bqkv{{bq, bk, bv, nullptr}};
    Ptr4 bo4{{bo, nullptr, nullptr, nullptr}};
    Ptr4 bg14{{bg1, bg1 + DM, nullptr, nullptr}};
    Ptr4 bg24{{bg2, nullptr, nullptr, nullptr}};
    Mask4 mnull{{nullptr, nullptr, nullptr, nullptr}};
    Mask4 mkAll{{am, dmk, em, hmk}};

    // ---- plan B: full-size GEMMs (8-phase 256^2), chunk only attention path ----
    const size_t xBytes = (size_t)NT * 4096 * 2;
    const size_t hBytes = (size_t)NT * 2048 * 2 + 512;
    int T2 = 0;
    {
        const int cands[4] = {8192, 4096, 2048, 1024};
        for (int ci = 0; ci < 4; ++ci) {
            int c = cands[ci];
            size_t chunkB = (size_t)c * 24576 + 512 + (size_t)c * 8192;
            size_t regHB = chunkB > hBytes ? chunkB : hBytes;
            if (fixed + xBytes + 256 + regHB + 4096 <= ws_size) { T2 = c; break; }
        }
    }

    if (T2 > 0) {
        char* regX = take(xBytes);
        size_t chunkB = (size_t)T2 * 24576 + 512 + (size_t)T2 * 8192;
        char* regH = take(chunkB > hBytes ? chunkB : hBytes);
        unsigned short* x = (unsigned short*)regX;      // x / attended (bf16)
        float* cons = (float*)regX;                     // consensus (f32)
        unsigned short* h = (unsigned short*)regH;
        unsigned short* qkv_c = (unsigned short*)regH;
        unsigned short* ctx_c = (unsigned short*)(regH + (size_t)T2 * 24576 + 512);

        // 1) masked modality projections: x[NT][4096]
        gemm_bt8<0><<<dim3(16, NT / 256), dim3(512), 131072, stream>>>(
            featB, Bt1, (void*)x, b1, mkAll, NT, 4 * DM, DM);
        // 2-4) attention path, chunked
        for (int t0 = 0; t0 < NT; t0 += T2) {
            unsigned short* xc = x + (size_t)t0 * 4096;
            gemm_bt8<1><<<dim3(12, 4 * T2 / 256), dim3(512), 131072, stream>>>(
                xc, Btqkv, (void*)qkv_c, bqkv, mnull, 4 * T2, 3 * DM, DM);
            attn4<<<dim3(T2), dim3(256), 0, stream>>>(qkv_c, ctx_c);
            gemm_bt8<1><<<dim3(4, 4 * T2 / 256), dim3(512), 131072, stream>>>(
                ctx_c, Bto, (void*)xc, bo4, mnull, 4 * T2, DM, DM);
        }
        // 5) gate MLP1 (+GELU): h[NT][2048]
        gemm_bt8<2><<<dim3(8, NT / 256), dim3(512), 131072, stream>>>(
            x, Btg1, (void*)h, bg14, mnull, NT, 2 * DM, 4 * DM);
        // 6) gate MLP2: cons f32 [NT][1024] (128^2 kernel: grid 512 blocks)
        gemm_bt<3><<<dim3(8, NT / BM), dim3(256), 0, stream>>>(
            h, Btg2, (void*)cons, bg24, mnull, NT, DM, 2 * DM);
        // 7) residual + LayerNorm
        resid_ln<<<dim3(NT), dim3(256), 0, stream>>>(cons, feat, lng, lnb, (float*)d_out);
        return;
    }

    // ---- plan A fallback (known-good fully-chunked 128^2 pipeline) ----
    const size_t avail = (ws_size > fixed) ? (ws_size - fixed) : 0;
    int T = 2048;
    while (T > 128 && ((size_t)T * 40960 + 4096) > avail) T >>= 1;
    unsigned short* bufA = (unsigned short*)take((size_t)T * 4096 * 2);
    unsigned short* bufB = (unsigned short*)take((size_t)T * 4 * 3072 * 2);
    unsigned short* bufC = (unsigned short*)take((size_t)T * 4 * 1024 * 2);

    const int nch = NT / T;
    for (int c = 0; c < nch; ++c) {
        const int t0 = c * T;
        Mask4 mk{{am + t0, dmk + t0, em + t0, hmk + t0}};
        gemm_bt<0><<<dim3(4 * DM / BN, T / BM), dim3(256), 0, stream>>>(
            featB + (size_t)t0 * DM, Bt1, (void*)bufA, b1, mk, T, 4 * DM, DM);
        gemm_bt<1><<<dim3(3 * DM / BN, 4 * T / BM), dim3(256), 0, stream>>>(
            bufA, Btqkv, (void*)bufB, bqkv, mnull, 4 * T, 3 * DM, DM);
        attn4<<<dim3(T), dim3(256), 0, stream>>>(bufB, bufC);
        gemm_bt<1><<<dim3(DM / BN, 4 * T / BM), dim3(256), 0, stream>>>(
            bufC, Bto, (void*)bufA, bo4, mnull, 4 * T, DM, DM);
        gemm_bt<2><<<dim3(2 * DM / BN, T / BM), dim3(256), 0, stream>>>(
            bufA, Btg1, (void*)bufC, bg14, mnull, T, 2 * DM, 4 * DM);
        gemm_bt<3><<<dim3(DM / BN, T / BM), dim3(256), 0, stream>>>(
            bufC, Btg2, (void*)bufB, bg24, mnull, T, DM, 2 * DM);
        resid_ln<<<dim3(T), dim3(256), 0, stream>>>(
            (const float*)bufB, feat + (size_t)t0 * DM, lng, lnb,
            (float*)d_out + (size_t)t0 * DM);
    }
}

// Round 5
// 706.092 us; speedup vs baseline: 1.5466x; 1.0270x over previous
//
#include <hip/hip_runtime.h>
#include <cstdint>
#include <cstddef>

// ---------------- constants ----------------
#define DM   1024          // model dim
#define NT   8192          // B*L tokens
#define HD   256
#define BM 128
#define BN 128
#define BK 32

typedef __attribute__((ext_vector_type(4))) float f32x4;
typedef __attribute__((ext_vector_type(8))) short bf16x8;

#define MF(a_, b_, c_) __builtin_amdgcn_mfma_f32_16x16x32_bf16(a_, b_, c_, 0, 0, 0)

__device__ __forceinline__ unsigned short f2bf(float f) {
    union { float f; uint32_t u; } v; v.f = f;
    return (unsigned short)((v.u + 0x7fffu + ((v.u >> 16) & 1u)) >> 16);
}
__device__ __forceinline__ float bf2f(unsigned short h) {
    union { uint32_t u; float f; } v; v.u = ((uint32_t)h) << 16;
    return v.f;
}

// T1: XCD-chunked bijective blockIdx swizzle (m157/m204). orig%8 = XCD;
// give each XCD a contiguous chunk of work ids so same-XCD neighbors share
// the A-panel (x-fastest decomposition). Bijective when nwg%8==0.
__device__ __forceinline__ int2 xcd_swizzle_xy() {
    int wid = blockIdx.y * gridDim.x + blockIdx.x;
    const int nwg = gridDim.x * gridDim.y;
    if ((nwg & 7) == 0) {
        const int per = nwg >> 3;
        wid = (wid & 7) * per + (wid >> 3);
    }
    int2 r;
    r.x = wid % gridDim.x;
    r.y = wid / gridDim.x;
    return r;
}

struct Ptr4 { const float* p[4]; };
struct Mask4 { const int* p[4]; };

// ---------------- prep kernels ----------------
__global__ void cvt_f32_to_bf16(const float* __restrict__ src,
                                unsigned short* __restrict__ dst, int n4) {
    int i = blockIdx.x * blockDim.x + threadIdx.x;
    if (i >= n4) return;
    float4 v = reinterpret_cast<const float4*>(src)[i];
    ushort4 o;
    o.x = f2bf(v.x); o.y = f2bf(v.y); o.z = f2bf(v.z); o.w = f2bf(v.w);
    reinterpret_cast<ushort4*>(dst)[i] = o;
}

// src fp32 [K][Nc] row-major  ->  dst bf16 [Nc][K] row-major (transposed)
__global__ void transpose_cvt(const float* __restrict__ src,
                              unsigned short* __restrict__ dst, int K, int Nc) {
    __shared__ float tile[32][33];
    const int n0 = blockIdx.x * 32, k0 = blockIdx.y * 32;
    const int tx = threadIdx.x & 31, ty = threadIdx.x >> 5;   // 32 x 8
#pragma unroll
    for (int i = 0; i < 4; ++i) {
        int k = ty + i * 8;
        tile[k][tx] = src[(size_t)(k0 + k) * Nc + n0 + tx];
    }
    __syncthreads();
#pragma unroll
    for (int i = 0; i < 4; ++i) {
        int n = ty + i * 8;
        dst[(size_t)(n0 + n) * K + k0 + tx] = f2bf(tile[tx][n]);
    }
}

__device__ __forceinline__ void gload16(const void* g, void* l) {
    __builtin_amdgcn_global_load_lds(
        (const __attribute__((address_space(1))) void*)g,
        (__attribute__((address_space(3))) void*)l, 16, 0, 0);
}

// ---------------- 128x128 GEMM (small grids / fallback) ----------------
// EPI: 0=(acc+bias)*mask->bf16  1=acc+bias->bf16  2=gelu->bf16  3=acc+bias->f32
template <int EPI>
__global__ void gemm_bt(const unsigned short* __restrict__ A,
                        const unsigned short* __restrict__ Bt,
                        void* __restrict__ out, Ptr4 bias, Mask4 masks,
                        int M, int Nc, int K) {
    __shared__ __attribute__((aligned(16))) unsigned short Als[BM * BK];
    __shared__ __attribute__((aligned(16))) unsigned short Bls[BN * BK];
    const int tid = threadIdx.x;
    const int wave = tid >> 6, lane = tid & 63;
    const int2 bxy = xcd_swizzle_xy();
    const int tileM = bxy.y * BM, tileN = bxy.x * BN;
    const int wr = wave >> 1, wc = wave & 1;

    f32x4 acc[4][4] = {};

    const int sr = tid >> 2;
    const int sc = (tid & 3) * 8;
    const unsigned short* aSrc0 = A + (size_t)(tileM + sr) * K + sc;
    const unsigned short* aSrc1 = A + (size_t)(tileM + 64 + sr) * K + sc;
    const unsigned short* bSrc0 = Bt + (size_t)(tileN + sr) * K + sc;
    const unsigned short* bSrc1 = Bt + (size_t)(tileN + 64 + sr) * K + sc;
    unsigned short* aDst0 = &Als[wave * 512];
    unsigned short* aDst1 = &Als[2048 + wave * 512];
    unsigned short* bDst0 = &Bls[wave * 512];
    unsigned short* bDst1 = &Bls[2048 + wave * 512];

    const int la = lane & 15;
    const int lb = (lane >> 4) * 8;

    for (int k0 = 0; k0 < K; k0 += BK) {
        gload16(aSrc0 + k0, aDst0);
        gload16(aSrc1 + k0, aDst1);
        gload16(bSrc0 + k0, bDst0);
        gload16(bSrc1 + k0, bDst1);
        __syncthreads();
        bf16x8 af[4], bfr[4];
#pragma unroll
        for (int m = 0; m < 4; ++m)
            af[m] = *reinterpret_cast<const bf16x8*>(&Als[(wr * 64 + m * 16 + la) * BK + lb]);
#pragma unroll
        for (int n = 0; n < 4; ++n)
            bfr[n] = *reinterpret_cast<const bf16x8*>(&Bls[(wc * 64 + n * 16 + la) * BK + lb]);
#pragma unroll
        for (int m = 0; m < 4; ++m)
#pragma unroll
            for (int n = 0; n < 4; ++n)
                acc[m][n] = MF(af[m], bfr[n], acc[m][n]);
        __syncthreads();
    }

    const float* bp = bias.p[tileN >> 10];
    const int rowT = tileM + wr * 64 + (lane >> 4) * 4;
    const int colT = tileN + wc * 64;
    unsigned short* outB = (unsigned short*)out;
    float* outF = (float*)out;

    float mv[4][4];
    if constexpr (EPI == 0) {
        const int* mp = masks.p[tileN >> 10];
#pragma unroll
        for (int m = 0; m < 4; ++m)
#pragma unroll
            for (int i = 0; i < 4; ++i)
                mv[m][i] = (float)mp[rowT + m * 16 + i];
    }

#pragma unroll
    for (int n = 0; n < 4; ++n) {
        const int gcol = colT + n * 16 + la;
        const float bv = bp[gcol & (DM - 1)];
#pragma unroll
        for (int m = 0; m < 4; ++m) {
#pragma unroll
            for (int i = 0; i < 4; ++i) {
                const int grow = rowT + m * 16 + i;
                float val = acc[m][n][i] + bv;
                if constexpr (EPI == 0) {
                    val *= mv[m][i];
                    outB[(size_t)grow * Nc + gcol] = f2bf(val);
                } else if constexpr (EPI == 1) {
                    outB[(size_t)grow * Nc + gcol] = f2bf(val);
                } else if constexpr (EPI == 2) {
                    val = 0.5f * val * (1.0f + erff(val * 0.70710678118654752f));
                    outB[(size_t)grow * Nc + gcol] = f2bf(val);
                } else {
                    outF[(size_t)grow * Nc + gcol] = val;
                }
            }
        }
    }
}

// ---------------- 256x256 8-phase GEMM (T1+T2+T3+T4+T5) ----------------
template <int EPI>
__global__ __launch_bounds__(512, 2)
void gemm_bt8(const unsigned short* __restrict__ A,
              const unsigned short* __restrict__ Bt,
              void* __restrict__ out, Ptr4 bias, Mask4 masks,
              int M, int Nc, int K) {
    extern __shared__ __attribute__((aligned(16))) unsigned short smem[];
    unsigned short* Asm = smem;            // [2][256*64]
    unsigned short* Bsm = smem + 32768;    // [2][256*64]
    const int tid = threadIdx.x;
    const int wave = tid >> 6, lane = tid & 63;
    const int wr = wave >> 2, wc = wave & 3;
    const int2 bxy = xcd_swizzle_xy();
    const int tileM = bxy.y * 256, tileN = bxy.x * 256;
    const int la = lane & 15, lh = lane >> 4;

    f32x4 acc[8][4] = {};

    const int srow = tid >> 3;
    const int scol = (tid & 7) * 16;
    const int sswz = (scol ^ ((srow & 7) << 4)) >> 1;   // pre-swizzled source elem off
    const unsigned short* aS = A + (size_t)(tileM + srow) * K + sswz;
    const unsigned short* bS = Bt + (size_t)(tileN + srow) * K + sswz;
    const int ra0 = (((lh * 16)) ^ ((la & 7) << 4)) >> 1;        // ks=0
    const int ra1 = ((64 + lh * 16) ^ ((la & 7) << 4)) >> 1;     // ks=1

    const int NKT = K >> 6;

#define STG_A(BUF, H, KO) do { \
    gload16(aS + (size_t)((H) * 128) * K + (KO), Asm + (BUF) * 16384 + ((H) * 128) * 64 + wave * 512); \
    gload16(aS + (size_t)((H) * 128 + 64) * K + (KO), Asm + (BUF) * 16384 + ((H) * 128 + 64) * 64 + wave * 512); \
} while (0)
#define STG_B(BUF, H, KO) do { \
    gload16(bS + (size_t)((H) * 128) * K + (KO), Bsm + (BUF) * 16384 + ((H) * 128) * 64 + wave * 512); \
    gload16(bS + (size_t)((H) * 128 + 64) * K + (KO), Bsm + (BUF) * 16384 + ((H) * 128 + 64) * 64 + wave * 512); \
} while (0)

    // prologue: stage K-tile 0 into buf 0
    STG_A(0, 0, 0); STG_A(0, 1, 0); STG_B(0, 0, 0); STG_B(0, 1, 0);

    int buf = 0;
    for (int kt = 0; kt < NKT; ++kt) {
        const size_t ko = (size_t)((kt + 1 < NKT) ? (kt + 1) : kt) * 64;  // clamped prefetch
        const int nb = buf ^ 1;
        const unsigned short* Ac = Asm + buf * 16384;
        const unsigned short* Bc = Bsm + buf * 16384;
        bf16x8 aR[8], bR[8];

        // ---- phase 1 ----
        STG_A(nb, 0, ko);
        asm volatile("s_waitcnt vmcnt(2)" ::: "memory");
        __builtin_amdgcn_s_barrier();
        asm volatile("" ::: "memory");
#pragma unroll
        for (int m = 0; m < 4; ++m) {
            aR[m * 2 + 0] = *reinterpret_cast<const bf16x8*>(&Ac[(wr * 128 + m * 16 + la) * 64 + ra0]);
            aR[m * 2 + 1] = *reinterpret_cast<const bf16x8*>(&Ac[(wr * 128 + m * 16 + la) * 64 + ra1]);
        }
#pragma unroll
        for (int n = 0; n < 2; ++n) {
            bR[n * 2 + 0] = *reinterpret_cast<const bf16x8*>(&Bc[(wc * 64 + n * 16 + la) * 64 + ra0]);
            bR[n * 2 + 1] = *reinterpret_cast<const bf16x8*>(&Bc[(wc * 64 + n * 16 + la) * 64 + ra1]);
        }
        __builtin_amdgcn_s_barrier();
        __builtin_amdgcn_s_setprio(1);
#pragma unroll
        for (int m = 0; m < 4; ++m)
#pragma unroll
            for (int n = 0; n < 2; ++n) {
                acc[m][n] = MF(aR[m * 2 + 0], bR[n * 2 + 0], acc[m][n]);
                acc[m][n] = MF(aR[m * 2 + 1], bR[n * 2 + 1], acc[m][n]);
            }
        __builtin_amdgcn_s_setprio(0);

        // ---- phase 2 ----
#pragma unroll
        for (int n = 2; n < 4; ++n) {
            bR[n * 2 + 0] = *reinterpret_cast<const bf16x8*>(&Bc[(wc * 64 + n * 16 + la) * 64 + ra0]);
            bR[n * 2 + 1] = *reinterpret_cast<const bf16x8*>(&Bc[(wc * 64 + n * 16 + la) * 64 + ra1]);
        }
        STG_A(nb, 1, ko);
        __builtin_amdgcn_s_barrier();
        __builtin_amdgcn_s_setprio(1);
#pragma unroll
        for (int m = 0; m < 4; ++m)
#pragma unroll
            for (int n = 2; n < 4; ++n) {
                acc[m][n] = MF(aR[m * 2 + 0], bR[n * 2 + 0], acc[m][n]);
                acc[m][n] = MF(aR[m * 2 + 1], bR[n * 2 + 1], acc[m][n]);
            }
        __builtin_amdgcn_s_setprio(0);

        // ---- phase 3 ----
#pragma unroll
        for (int m = 0; m < 4; ++m) {
            aR[m * 2 + 0] = *reinterpret_cast<const bf16x8*>(&Ac[(wr * 128 + (m + 4) * 16 + la) * 64 + ra0]);
            aR[m * 2 + 1] = *reinterpret_cast<const bf16x8*>(&Ac[(wr * 128 + (m + 4) * 16 + la) * 64 + ra1]);
        }
        STG_B(nb, 0, ko);
        __builtin_amdgcn_s_barrier();
        __builtin_amdgcn_s_setprio(1);
#pragma unroll
        for (int m = 0; m < 4; ++m)
#pragma unroll
            for (int n = 0; n < 2; ++n) {
                acc[m + 4][n] = MF(aR[m * 2 + 0], bR[n * 2 + 0], acc[m + 4][n]);
                acc[m + 4][n] = MF(aR[m * 2 + 1], bR[n * 2 + 1], acc[m + 4][n]);
            }
        __builtin_amdgcn_s_setprio(0);

        // ---- phase 4 ----
        STG_B(nb, 1, ko);
        __builtin_amdgcn_s_barrier();
        __builtin_amdgcn_s_setprio(1);
#pragma unroll
        for (int m = 0; m < 4; ++m)
#pragma unroll
            for (int n = 2; n < 4; ++n) {
                acc[m + 4][n] = MF(aR[m * 2 + 0], bR[n * 2 + 0], acc[m + 4][n]);
                acc[m + 4][n] = MF(aR[m * 2 + 1], bR[n * 2 + 1], acc[m + 4][n]);
            }
        __builtin_amdgcn_s_setprio(0);
        asm volatile("" ::: "memory");
        __builtin_amdgcn_s_barrier();
        buf = nb;
    }
#undef STG_A
#undef STG_B

    // ---- epilogue ----
    const float* bp = bias.p[tileN >> 10];
    unsigned short* outB = (unsigned short*)out;
    float* outF = (float*)out;
    const int* mp = (EPI == 0) ? masks.p[tileN >> 10] : nullptr;

#pragma unroll
    for (int n = 0; n < 4; ++n) {
        const int gcol = tileN + wc * 64 + n * 16 + la;
        const float bv = bp[gcol & (DM - 1)];
#pragma unroll
        for (int m = 0; m < 8; ++m) {
#pragma unroll
            for (int i = 0; i < 4; ++i) {
                const int grow = tileM + wr * 128 + m * 16 + lh * 4 + i;
                float val = acc[m][n][i] + bv;
                if constexpr (EPI == 0) {
                    val *= (float)mp[grow];
                    outB[(size_t)grow * Nc + gcol] = f2bf(val);
                } else if constexpr (EPI == 1) {
                    outB[(size_t)grow * Nc + gcol] = f2bf(val);
                } else if constexpr (EPI == 2) {
                    val = 0.5f * val * (1.0f + erff(val * 0.70710678118654752f));
                    outB[(size_t)grow * Nc + gcol] = f2bf(val);
                } else {
                    outF[(size_t)grow * Nc + gcol] = val;
                }
            }
        }
    }
}

// ---------------- tiny 4-token attention ----------------
__global__ void attn4(const unsigned short* __restrict__ qkv,
                      unsigned short* __restrict__ ctx) {
    const int n = blockIdx.x;
    const int h = threadIdx.x >> 6;
    const int lane = threadIdx.x & 63;
    const size_t base = (size_t)n * 4 * 3072 + h * HD + lane * 4;

    float q[4][4], k[4][4], v[4][4];
#pragma unroll
    for (int m = 0; m < 4; ++m) {
        ushort4 uq = *reinterpret_cast<const ushort4*>(&qkv[base + (size_t)m * 3072]);
        ushort4 uk = *reinterpret_cast<const ushort4*>(&qkv[base + (size_t)m * 3072 + 1024]);
        ushort4 uv = *reinterpret_cast<const ushort4*>(&qkv[base + (size_t)m * 3072 + 2048]);
        q[m][0] = bf2f(uq.x); q[m][1] = bf2f(uq.y); q[m][2] = bf2f(uq.z); q[m][3] = bf2f(uq.w);
        k[m][0] = bf2f(uk.x); k[m][1] = bf2f(uk.y); k[m][2] = bf2f(uk.z); k[m][3] = bf2f(uk.w);
        v[m][0] = bf2f(uv.x); v[m][1] = bf2f(uv.y); v[m][2] = bf2f(uv.z); v[m][3] = bf2f(uv.w);
    }

    float s[4][4];
#pragma unroll
    for (int qi = 0; qi < 4; ++qi)
#pragma unroll
        for (int ki = 0; ki < 4; ++ki)
            s[qi][ki] = q[qi][0] * k[ki][0] + q[qi][1] * k[ki][1] +
                        q[qi][2] * k[ki][2] + q[qi][3] * k[ki][3];
#pragma unroll
    for (int off = 32; off >= 1; off >>= 1) {
#pragma unroll
        for (int qi = 0; qi < 4; ++qi)
#pragma unroll
            for (int ki = 0; ki < 4; ++ki)
                s[qi][ki] += __shfl_xor(s[qi][ki], off, 64);
    }

#pragma unroll
    for (int qi = 0; qi < 4; ++qi) {
        float s0 = s[qi][0] * 0.0625f, s1 = s[qi][1] * 0.0625f;
        float s2 = s[qi][2] * 0.0625f, s3 = s[qi][3] * 0.0625f;
        float mx = fmaxf(fmaxf(s0, s1), fmaxf(s2, s3));
        float e0 = __expf(s0 - mx), e1 = __expf(s1 - mx);
        float e2 = __expf(s2 - mx), e3 = __expf(s3 - mx);
        float inv = 1.0f / (e0 + e1 + e2 + e3);
        e0 *= inv; e1 *= inv; e2 *= inv; e3 *= inv;
        ushort4 o;
        o.x = f2bf(e0 * v[0][0] + e1 * v[1][0] + e2 * v[2][0] + e3 * v[3][0]);
        o.y = f2bf(e0 * v[0][1] + e1 * v[1][1] + e2 * v[2][1] + e3 * v[3][1]);
        o.z = f2bf(e0 * v[0][2] + e1 * v[1][2] + e2 * v[2][2] + e3 * v[3][2]);
        o.w = f2bf(e0 * v[0][3] + e1 * v[1][3] + e2 * v[2][3] + e3 * v[3][3]);
        *reinterpret_cast<ushort4*>(&ctx[(size_t)(n * 4 + qi) * 1024 + h * HD + lane * 4]) = o;
    }
}

// ---------------- residual + LayerNorm ----------------
__global__ void resid_ln(const float* __restrict__ cons, const float* __restrict__ feat,
                         const float* __restrict__ g, const float* __restrict__ b,
                         float* __restrict__ out) {
    const int row = blockIdx.x;
    const int t = threadIdx.x;
    const size_t base = (size_t)row * DM + t * 4;
    float4 c = *reinterpret_cast<const float4*>(&cons[base]);
    float4 f = *reinterpret_cast<const float4*>(&feat[base]);
    float y0 = c.x + f.x, y1 = c.y + f.y, y2 = c.z + f.z, y3 = c.w + f.w;
    float sum = y0 + y1 + y2 + y3;
    float sq = y0 * y0 + y1 * y1 + y2 * y2 + y3 * y3;
#pragma unroll
    for (int off = 32; off >= 1; off >>= 1) {
        sum += __shfl_xor(sum, off, 64);
        sq += __shfl_xor(sq, off, 64);
    }
    __shared__ float rs[4], rq[4];
    const int wv = t >> 6, ln = t & 63;
    if (ln == 0) { rs[wv] = sum; rq[wv] = sq; }
    __syncthreads();
    sum = rs[0] + rs[1] + rs[2] + rs[3];
    sq = rq[0] + rq[1] + rq[2] + rq[3];
    const float mu = sum * (1.0f / DM);
    const float var = sq * (1.0f / DM) - mu * mu;
    const float rstd = rsqrtf(var + 1e-5f);
    float4 gg = *reinterpret_cast<const float4*>(&g[t * 4]);
    float4 bb = *reinterpret_cast<const float4*>(&b[t * 4]);
    float4 o;
    o.x = (y0 - mu) * rstd * gg.x + bb.x;
    o.y = (y1 - mu) * rstd * gg.y + bb.y;
    o.z = (y2 - mu) * rstd * gg.z + bb.z;
    o.w = (y3 - mu) * rstd * gg.w + bb.w;
    *reinterpret_cast<float4*>(&out[base]) = o;
}

// ---------------- launch ----------------
extern "C" void kernel_launch(void* const* d_in, const int* in_sizes, int n_in,
                              void* d_out, int out_size, void* d_ws, size_t ws_size,
                              hipStream_t stream) {
    (void)in_sizes; (void)n_in; (void)out_size;
    const float* feat = (const float*)d_in[0];
    const int* am = (const int*)d_in[1];
    const int* dmk = (const int*)d_in[2];
    const int* em = (const int*)d_in[3];
    const int* hmk = (const int*)d_in[4];
    const float* Wa = (const float*)d_in[5];  const float* ba = (const float*)d_in[6];
    const float* Wd = (const float*)d_in[7];  const float* bd = (const float*)d_in[8];
    const float* We = (const float*)d_in[9];  const float* be = (const float*)d_in[10];
    const float* Wh = (const float*)d_in[11]; const float* bh = (const float*)d_in[12];
    const float* Wq = (const float*)d_in[13]; const float* bq = (const float*)d_in[14];
    const float* Wk = (const float*)d_in[15]; const float* bk = (const float*)d_in[16];
    const float* Wv = (const float*)d_in[17]; const float* bv = (const float*)d_in[18];
    const float* Wo = (const float*)d_in[19]; const float* bo = (const float*)d_in[20];
    const float* Wg1 = (const float*)d_in[21]; const float* bg1 = (const float*)d_in[22];
    const float* Wg2 = (const float*)d_in[23]; const float* bg2 = (const float*)d_in[24];
    const float* lng = (const float*)d_in[25]; const float* lnb = (const float*)d_in[26];

    hipFuncSetAttribute(reinterpret_cast<const void*>(&gemm_bt8<0>),
                        hipFuncAttributeMaxDynamicSharedMemorySize, 131072);
    hipFuncSetAttribute(reinterpret_cast<const void*>(&gemm_bt8<1>),
                        hipFuncAttributeMaxDynamicSharedMemorySize, 131072);
    hipFuncSetAttribute(reinterpret_cast<const void*>(&gemm_bt8<2>),
                        hipFuncAttributeMaxDynamicSharedMemorySize, 131072);

    char* ws = (char*)d_ws;
    size_t off = 0;
    auto take = [&](size_t bytes) -> char* {
        char* r = ws + off;
        off = (off + bytes + 255) & ~(size_t)255;
        return r;
    };
    // ---- fixed weight/feature allocations: ~54.6 MB ----
    unsigned short* featB = (unsigned short*)take((size_t)NT * DM * 2);
    unsigned short* Bt1   = (unsigned short*)take((size_t)4 * DM * DM * 2);
    unsigned short* Btqkv = (unsigned short*)take((size_t)3 * DM * DM * 2);
    unsigned short* Bto   = (unsigned short*)take((size_t)DM * DM * 2);
    unsigned short* Btg1  = (unsigned short*)take((size_t)2 * DM * 4 * DM * 2);
    unsigned short* Btg2  = (unsigned short*)take((size_t)DM * 2 * DM * 2);
    const size_t fixed = off;

    cvt_f32_to_bf16<<<dim3((NT * DM / 4 + 255) / 256), dim3(256), 0, stream>>>(
        feat, featB, NT * DM / 4);
    auto tl = [&](const float* src, unsigned short* dst, int K, int Nc) {
        transpose_cvt<<<dim3(Nc / 32, K / 32), dim3(256), 0, stream>>>(src, dst, K, Nc);
    };
    tl(Wa, Bt1, DM, DM);
    tl(Wd, Bt1 + (size_t)DM * DM, DM, DM);
    tl(We, Bt1 + (size_t)2 * DM * DM, DM, DM);
    tl(Wh, Bt1 + (size_t)3 * DM * DM, DM, DM);
    tl(Wq, Btqkv, DM, DM);
    tl(Wk, Btqkv + (size_t)DM * DM, DM, DM);
    tl(Wv, Btqkv + (size_t)2 * DM * DM, DM, DM);
    tl(Wo, Bto, DM, DM);
    tl(Wg1, Btg1, 4 * DM, 2 * DM);
    tl(Wg2, Btg2, 2 * DM, DM);

    Ptr4 b1{{ba, bd, be, bh}};
    Ptr4 bqkv{{bq, bk, bv, nullptr}};
    Ptr4 bo4{{bo, nullptr, nullptr, nullptr}};
    Ptr4 bg14{{bg1, bg1 + DM, nullptr, nullptr}};
    Ptr4 bg24{{bg2, nullptr, nullptr, nullptr}};
    Mask4 mnull{{nullptr, nullptr, nullptr, nullptr}};
    Mask4 mkAll{{am, dmk, em, hmk}};

    // ---- plan B: full-size GEMMs (8-phase 256^2), chunk only attention path ----
    const size_t xBytes = (size_t)NT * 4096 * 2;
    const size_t hBytes = (size_t)NT * 2048 * 2 + 512;
    int T2 = 0;
    {
        const int cands[4] = {8192, 4096, 2048, 1024};
        for (int ci = 0; ci < 4; ++ci) {
            int c = cands[ci];
            size_t chunkB = (size_t)c * 24576 + 512 + (size_t)c * 8192;
            size_t regHB = chunkB > hBytes ? chunkB : hBytes;
            if (fixed + xBytes + 256 + regHB + 4096 <= ws_size) { T2 = c; break; }
        }
    }

    if (T2 > 0) {
        char* regX = take(xBytes);
        size_t chunkB = (size_t)T2 * 24576 + 512 + (size_t)T2 * 8192;
        char* regH = take(chunkB > hBytes ? chunkB : hBytes);
        unsigned short* x = (unsigned short*)regX;      // x / attended (bf16)
        float* cons = (float*)regX;                     // consensus (f32)
        unsigned short* h = (unsigned short*)regH;
        unsigned short* qkv_c = (unsigned short*)regH;
        unsigned short* ctx_c = (unsigned short*)(regH + (size_t)T2 * 24576 + 512);

        // 1) masked modality projections: x[NT][4096]
        gemm_bt8<0><<<dim3(16, NT / 256), dim3(512), 131072, stream>>>(
            featB, Bt1, (void*)x, b1, mkAll, NT, 4 * DM, DM);
        // 2-4) attention path, chunked
        for (int t0 = 0; t0 < NT; t0 += T2) {
            unsigned short* xc = x + (size_t)t0 * 4096;
            gemm_bt8<1><<<dim3(12, 4 * T2 / 256), dim3(512), 131072, stream>>>(
                xc, Btqkv, (void*)qkv_c, bqkv, mnull, 4 * T2, 3 * DM, DM);
            attn4<<<dim3(T2), dim3(256), 0, stream>>>(qkv_c, ctx_c);
            gemm_bt8<1><<<dim3(4, 4 * T2 / 256), dim3(512), 131072, stream>>>(
                ctx_c, Bto, (void*)xc, bo4, mnull, 4 * T2, DM, DM);
        }
        // 5) gate MLP1 (+GELU): h[NT][2048]
        gemm_bt8<2><<<dim3(8, NT / 256), dim3(512), 131072, stream>>>(
            x, Btg1, (void*)h, bg14, mnull, NT, 2 * DM, 4 * DM);
        // 6) gate MLP2: cons f32 [NT][1024]
        gemm_bt<3><<<dim3(8, NT / BM), dim3(256), 0, stream>>>(
            h, Btg2, (void*)cons, bg24, mnull, NT, DM, 2 * DM);
        // 7) residual + LayerNorm
        resid_ln<<<dim3(NT), dim3(256), 0, stream>>>(cons, feat, lng, lnb, (float*)d_out);
        return;
    }

    // ---- plan A fallback (known-good fully-chunked 128^2 pipeline) ----
    const size_t avail = (ws_size > fixed) ? (ws_size - fixed) : 0;
    int T = 2048;
    while (T > 128 && ((size_t)T * 40960 + 4096) > avail) T >>= 1;
    unsigned short* bufA = (unsigned short*)take((size_t)T * 4096 * 2);
    unsigned short* bufB = (unsigned short*)take((size_t)T * 4 * 3072 * 2);
    unsigned short* bufC = (unsigned short*)take((size_t)T * 4 * 1024 * 2);

    const int nch = NT / T;
    for (int c = 0; c < nch; ++c) {
        const int t0 = c * T;
        Mask4 mk{{am + t0, dmk + t0, em + t0, hmk + t0}};
        gemm_bt<0><<<dim3(4 * DM / BN, T / BM), dim3(256), 0, stream>>>(
            featB + (size_t)t0 * DM, Bt1, (void*)bufA, b1, mk, T, 4 * DM, DM);
        gemm_bt<1><<<dim3(3 * DM / BN, 4 * T / BM), dim3(256), 0, stream>>>(
            bufA, Btqkv, (void*)bufB, bqkv, mnull, 4 * T, 3 * DM, DM);
        attn4<<<dim3(T), dim3(256), 0, stream>>>(bufB, bufC);
        gemm_bt<1><<<dim3(DM / BN, 4 * T / BM), dim3(256), 0, stream>>>(
            bufC, Bto, (void*)bufA, bo4, mnull, 4 * T, DM, DM);
        gemm_bt<2><<<dim3(2 * DM / BN, T / BM), dim3(256), 0, stream>>>(
            bufA, Btg1, (void*)bufC, bg14, mnull, T, 2 * DM, 4 * DM);
        gemm_bt<3><<<dim3(DM / BN, T / BM), dim3(256), 0, stream>>>(
            bufC, Btg2, (void*)bufB, bg24, mnull, T, DM, 2 * DM);
        resid_ln<<<dim3(T), dim3(256), 0, stream>>>(
            (const float*)bufB, feat + (size_t)t0 * DM, lng, lnb,
            (float*)d_out + (size_t)t0 * DM);
    }
}

// Round 6
// 705.016 us; speedup vs baseline: 1.5490x; 1.0015x over previous
//
#include <hip/hip_runtime.h>
#include <cstdint>
#include <cstddef>

// ---------------- constants ----------------
#define DM   1024          // model dim
#define NT   8192          // B*L tokens
#define HD   256
#define BM 128
#define BN 128
#define BK 32

typedef __attribute__((ext_vector_type(4))) float f32x4;
typedef __attribute__((ext_vector_type(8))) short bf16x8;

#define MF(a_, b_, c_) __builtin_amdgcn_mfma_f32_16x16x32_bf16(a_, b_, c_, 0, 0, 0)

__device__ __forceinline__ unsigned short f2bf(float f) {
    union { float f; uint32_t u; } v; v.f = f;
    return (unsigned short)((v.u + 0x7fffu + ((v.u >> 16) & 1u)) >> 16);
}
__device__ __forceinline__ float bf2f(unsigned short h) {
    union { uint32_t u; float f; } v; v.u = ((uint32_t)h) << 16;
    return v.f;
}

// T1: XCD-chunked bijective blockIdx swizzle. orig%8 = XCD; contiguous chunk
// per XCD so same-XCD neighbors share A-panels. Bijective when nwg%8==0.
__device__ __forceinline__ int2 xcd_swizzle_xy() {
    int wid = blockIdx.y * gridDim.x + blockIdx.x;
    const int nwg = gridDim.x * gridDim.y;
    if ((nwg & 7) == 0) {
        const int per = nwg >> 3;
        wid = (wid & 7) * per + (wid >> 3);
    }
    int2 r;
    r.x = wid % gridDim.x;
    r.y = wid / gridDim.x;
    return r;
}

struct Ptr4 { const float* p[4]; };
struct Mask4 { const int* p[4]; };

// ---------------- prep kernels ----------------
__global__ void cvt_f32_to_bf16(const float* __restrict__ src,
                                unsigned short* __restrict__ dst, int n4) {
    int i = blockIdx.x * blockDim.x + threadIdx.x;
    if (i >= n4) return;
    float4 v = reinterpret_cast<const float4*>(src)[i];
    ushort4 o;
    o.x = f2bf(v.x); o.y = f2bf(v.y); o.z = f2bf(v.z); o.w = f2bf(v.w);
    reinterpret_cast<ushort4*>(dst)[i] = o;
}

// src fp32 [K][Nc] row-major  ->  dst bf16 [Nc][K] row-major (transposed)
__global__ void transpose_cvt(const float* __restrict__ src,
                              unsigned short* __restrict__ dst, int K, int Nc) {
    __shared__ float tile[32][33];
    const int n0 = blockIdx.x * 32, k0 = blockIdx.y * 32;
    const int tx = threadIdx.x & 31, ty = threadIdx.x >> 5;   // 32 x 8
#pragma unroll
    for (int i = 0; i < 4; ++i) {
        int k = ty + i * 8;
        tile[k][tx] = src[(size_t)(k0 + k) * Nc + n0 + tx];
    }
    __syncthreads();
#pragma unroll
    for (int i = 0; i < 4; ++i) {
        int n = ty + i * 8;
        dst[(size_t)(n0 + n) * K + k0 + tx] = f2bf(tile[tx][n]);
    }
}

__device__ __forceinline__ void gload16(const void* g, void* l) {
    __builtin_amdgcn_global_load_lds(
        (const __attribute__((address_space(1))) void*)g,
        (__attribute__((address_space(3))) void*)l, 16, 0, 0);
}

// ---------------- 128x128 GEMM (small grids / fallback) ----------------
// EPI: 0=(acc+bias)*mask->bf16  1=acc+bias->bf16  2=gelu->bf16  3=acc+bias->f32
template <int EPI>
__global__ void gemm_bt(const unsigned short* __restrict__ A,
                        const unsigned short* __restrict__ Bt,
                        void* __restrict__ out, Ptr4 bias, Mask4 masks,
                        int M, int Nc, int K) {
    __shared__ __attribute__((aligned(16))) unsigned short Als[BM * BK];
    __shared__ __attribute__((aligned(16))) unsigned short Bls[BN * BK];
    const int tid = threadIdx.x;
    const int wave = tid >> 6, lane = tid & 63;
    const int2 bxy = xcd_swizzle_xy();
    const int tileM = bxy.y * BM, tileN = bxy.x * BN;
    const int wr = wave >> 1, wc = wave & 1;

    f32x4 acc[4][4] = {};

    const int sr = tid >> 2;
    const int sc = (tid & 3) * 8;
    const unsigned short* aSrc0 = A + (size_t)(tileM + sr) * K + sc;
    const unsigned short* aSrc1 = A + (size_t)(tileM + 64 + sr) * K + sc;
    const unsigned short* bSrc0 = Bt + (size_t)(tileN + sr) * K + sc;
    const unsigned short* bSrc1 = Bt + (size_t)(tileN + 64 + sr) * K + sc;
    unsigned short* aDst0 = &Als[wave * 512];
    unsigned short* aDst1 = &Als[2048 + wave * 512];
    unsigned short* bDst0 = &Bls[wave * 512];
    unsigned short* bDst1 = &Bls[2048 + wave * 512];

    const int la = lane & 15;
    const int lb = (lane >> 4) * 8;

    for (int k0 = 0; k0 < K; k0 += BK) {
        gload16(aSrc0 + k0, aDst0);
        gload16(aSrc1 + k0, aDst1);
        gload16(bSrc0 + k0, bDst0);
        gload16(bSrc1 + k0, bDst1);
        __syncthreads();
        bf16x8 af[4], bfr[4];
#pragma unroll
        for (int m = 0; m < 4; ++m)
            af[m] = *reinterpret_cast<const bf16x8*>(&Als[(wr * 64 + m * 16 + la) * BK + lb]);
#pragma unroll
        for (int n = 0; n < 4; ++n)
            bfr[n] = *reinterpret_cast<const bf16x8*>(&Bls[(wc * 64 + n * 16 + la) * BK + lb]);
#pragma unroll
        for (int m = 0; m < 4; ++m)
#pragma unroll
            for (int n = 0; n < 4; ++n)
                acc[m][n] = MF(af[m], bfr[n], acc[m][n]);
        __syncthreads();
    }

    const float* bp = bias.p[tileN >> 10];
    const int rowT = tileM + wr * 64 + (lane >> 4) * 4;
    const int colT = tileN + wc * 64;
    unsigned short* outB = (unsigned short*)out;
    float* outF = (float*)out;

    float mv[4][4];
    if constexpr (EPI == 0) {
        const int* mp = masks.p[tileN >> 10];
#pragma unroll
        for (int m = 0; m < 4; ++m)
#pragma unroll
            for (int i = 0; i < 4; ++i)
                mv[m][i] = (float)mp[rowT + m * 16 + i];
    }

#pragma unroll
    for (int n = 0; n < 4; ++n) {
        const int gcol = colT + n * 16 + la;
        const float bv = bp[gcol & (DM - 1)];
#pragma unroll
        for (int m = 0; m < 4; ++m) {
#pragma unroll
            for (int i = 0; i < 4; ++i) {
                const int grow = rowT + m * 16 + i;
                float val = acc[m][n][i] + bv;
                if constexpr (EPI == 0) {
                    val *= mv[m][i];
                    outB[(size_t)grow * Nc + gcol] = f2bf(val);
                } else if constexpr (EPI == 1) {
                    outB[(size_t)grow * Nc + gcol] = f2bf(val);
                } else if constexpr (EPI == 2) {
                    val = 0.5f * val * (1.0f + erff(val * 0.70710678118654752f));
                    outB[(size_t)grow * Nc + gcol] = f2bf(val);
                } else {
                    outF[(size_t)grow * Nc + gcol] = val;
                }
            }
        }
    }
}

// ---------------- 256x256 4-phase/K-tile GEMM (T1+T2+T3+T4+T5) ----------------
// Deep prefetch: ALL 8 next-tile loads issued in phases 1-2; phases 3-4 pure
// compute; single vmcnt(4) gate per K-tile placed after phase-1 issue (never
// drains to 0). Min load lead ~3 phases.
template <int EPI>
__global__ __launch_bounds__(512, 2)
void gemm_bt8(const unsigned short* __restrict__ A,
              const unsigned short* __restrict__ Bt,
              void* __restrict__ out, Ptr4 bias, Mask4 masks,
              int M, int Nc, int K) {
    extern __shared__ __attribute__((aligned(16))) unsigned short smem[];
    unsigned short* Asm = smem;            // [2][256*64]
    unsigned short* Bsm = smem + 32768;    // [2][256*64]
    const int tid = threadIdx.x;
    const int wave = tid >> 6, lane = tid & 63;
    const int wr = wave >> 2, wc = wave & 3;
    const int2 bxy = xcd_swizzle_xy();
    const int tileM = bxy.y * 256, tileN = bxy.x * 256;
    const int la = lane & 15, lh = lane >> 4;

    f32x4 acc[8][4] = {};

    const int srow = tid >> 3;
    const int scol = (tid & 7) * 16;
    const int sswz = (scol ^ ((srow & 7) << 4)) >> 1;   // pre-swizzled source elem off
    const unsigned short* aS = A + (size_t)(tileM + srow) * K + sswz;
    const unsigned short* bS = Bt + (size_t)(tileN + srow) * K + sswz;
    const int ra0 = (((lh * 16)) ^ ((la & 7) << 4)) >> 1;        // ks=0
    const int ra1 = ((64 + lh * 16) ^ ((la & 7) << 4)) >> 1;     // ks=1

    const int NKT = K >> 6;

#define STG_A(BUF, H, KO) do { \
    gload16(aS + (size_t)((H) * 128) * K + (KO), Asm + (BUF) * 16384 + ((H) * 128) * 64 + wave * 512); \
    gload16(aS + (size_t)((H) * 128 + 64) * K + (KO), Asm + (BUF) * 16384 + ((H) * 128 + 64) * 64 + wave * 512); \
} while (0)
#define STG_B(BUF, H, KO) do { \
    gload16(bS + (size_t)((H) * 128) * K + (KO), Bsm + (BUF) * 16384 + ((H) * 128) * 64 + wave * 512); \
    gload16(bS + (size_t)((H) * 128 + 64) * K + (KO), Bsm + (BUF) * 16384 + ((H) * 128 + 64) * 64 + wave * 512); \
} while (0)

    // prologue: stage K-tile 0 into buf 0
    STG_A(0, 0, 0); STG_A(0, 1, 0); STG_B(0, 0, 0); STG_B(0, 1, 0);

    int buf = 0;
    for (int kt = 0; kt < NKT; ++kt) {
        const size_t ko = (size_t)((kt + 1 < NKT) ? (kt + 1) : kt) * 64;  // clamped prefetch
        const int nb = buf ^ 1;
        const unsigned short* Ac = Asm + buf * 16384;
        const unsigned short* Bc = Bsm + buf * 16384;
        bf16x8 aR[8], bR[8];

        // ---- phase 1: issue A(next) x4; gate tile kt (vmcnt keeps 4 in flight);
        //      read A[m0-3],B[n0-1]; MFMA q00 ----
        STG_A(nb, 0, ko);
        STG_A(nb, 1, ko);
        asm volatile("s_waitcnt vmcnt(4)" ::: "memory");
        __builtin_amdgcn_s_barrier();
        asm volatile("" ::: "memory");
#pragma unroll
        for (int m = 0; m < 4; ++m) {
            aR[m * 2 + 0] = *reinterpret_cast<const bf16x8*>(&Ac[(wr * 128 + m * 16 + la) * 64 + ra0]);
            aR[m * 2 + 1] = *reinterpret_cast<const bf16x8*>(&Ac[(wr * 128 + m * 16 + la) * 64 + ra1]);
        }
#pragma unroll
        for (int n = 0; n < 2; ++n) {
            bR[n * 2 + 0] = *reinterpret_cast<const bf16x8*>(&Bc[(wc * 64 + n * 16 + la) * 64 + ra0]);
            bR[n * 2 + 1] = *reinterpret_cast<const bf16x8*>(&Bc[(wc * 64 + n * 16 + la) * 64 + ra1]);
        }
        __builtin_amdgcn_s_barrier();
        __builtin_amdgcn_s_setprio(1);
#pragma unroll
        for (int m = 0; m < 4; ++m)
#pragma unroll
            for (int n = 0; n < 2; ++n) {
                acc[m][n] = MF(aR[m * 2 + 0], bR[n * 2 + 0], acc[m][n]);
                acc[m][n] = MF(aR[m * 2 + 1], bR[n * 2 + 1], acc[m][n]);
            }
        __builtin_amdgcn_s_setprio(0);

        // ---- phase 2: read B[n2-3]; issue B(next) x4; MFMA q01 ----
#pragma unroll
        for (int n = 2; n < 4; ++n) {
            bR[n * 2 + 0] = *reinterpret_cast<const bf16x8*>(&Bc[(wc * 64 + n * 16 + la) * 64 + ra0]);
            bR[n * 2 + 1] = *reinterpret_cast<const bf16x8*>(&Bc[(wc * 64 + n * 16 + la) * 64 + ra1]);
        }
        STG_B(nb, 0, ko);
        STG_B(nb, 1, ko);
        __builtin_amdgcn_s_barrier();
        __builtin_amdgcn_s_setprio(1);
#pragma unroll
        for (int m = 0; m < 4; ++m)
#pragma unroll
            for (int n = 2; n < 4; ++n) {
                acc[m][n] = MF(aR[m * 2 + 0], bR[n * 2 + 0], acc[m][n]);
                acc[m][n] = MF(aR[m * 2 + 1], bR[n * 2 + 1], acc[m][n]);
            }
        __builtin_amdgcn_s_setprio(0);

        // ---- phase 3: read A[m4-7]; MFMA q10 (pure compute, loads in flight) ----
#pragma unroll
        for (int m = 0; m < 4; ++m) {
            aR[m * 2 + 0] = *reinterpret_cast<const bf16x8*>(&Ac[(wr * 128 + (m + 4) * 16 + la) * 64 + ra0]);
            aR[m * 2 + 1] = *reinterpret_cast<const bf16x8*>(&Ac[(wr * 128 + (m + 4) * 16 + la) * 64 + ra1]);
        }
        __builtin_amdgcn_s_barrier();
        __builtin_amdgcn_s_setprio(1);
#pragma unroll
        for (int m = 0; m < 4; ++m)
#pragma unroll
            for (int n = 0; n < 2; ++n) {
                acc[m + 4][n] = MF(aR[m * 2 + 0], bR[n * 2 + 0], acc[m + 4][n]);
                acc[m + 4][n] = MF(aR[m * 2 + 1], bR[n * 2 + 1], acc[m + 4][n]);
            }
        __builtin_amdgcn_s_setprio(0);

        // ---- phase 4: MFMA q11; end-of-tile barrier (buf reads complete) ----
        __builtin_amdgcn_s_setprio(1);
#pragma unroll
        for (int m = 0; m < 4; ++m)
#pragma unroll
            for (int n = 2; n < 4; ++n) {
                acc[m + 4][n] = MF(aR[m * 2 + 0], bR[n * 2 + 0], acc[m + 4][n]);
                acc[m + 4][n] = MF(aR[m * 2 + 1], bR[n * 2 + 1], acc[m + 4][n]);
            }
        __builtin_amdgcn_s_setprio(0);
        asm volatile("" ::: "memory");
        __builtin_amdgcn_s_barrier();
        buf = nb;
    }
#undef STG_A
#undef STG_B

    // ---- epilogue ----
    const float* bp = bias.p[tileN >> 10];
    unsigned short* outB = (unsigned short*)out;
    float* outF = (float*)out;
    const int* mp = (EPI == 0) ? masks.p[tileN >> 10] : nullptr;

#pragma unroll
    for (int n = 0; n < 4; ++n) {
        const int gcol = tileN + wc * 64 + n * 16 + la;
        const float bv = bp[gcol & (DM - 1)];
#pragma unroll
        for (int m = 0; m < 8; ++m) {
#pragma unroll
            for (int i = 0; i < 4; ++i) {
                const int grow = tileM + wr * 128 + m * 16 + lh * 4 + i;
                float val = acc[m][n][i] + bv;
                if constexpr (EPI == 0) {
                    val *= (float)mp[grow];
                    outB[(size_t)grow * Nc + gcol] = f2bf(val);
                } else if constexpr (EPI == 1) {
                    outB[(size_t)grow * Nc + gcol] = f2bf(val);
                } else if constexpr (EPI == 2) {
                    val = 0.5f * val * (1.0f + erff(val * 0.70710678118654752f));
                    outB[(size_t)grow * Nc + gcol] = f2bf(val);
                } else {
                    outF[(size_t)grow * Nc + gcol] = val;
                }
            }
        }
    }
}

// ---------------- tiny 4-token attention ----------------
__global__ void attn4(const unsigned short* __restrict__ qkv,
                      unsigned short* __restrict__ ctx) {
    const int n = blockIdx.x;
    const int h = threadIdx.x >> 6;
    const int lane = threadIdx.x & 63;
    const size_t base = (size_t)n * 4 * 3072 + h * HD + lane * 4;

    float q[4][4], k[4][4], v[4][4];
#pragma unroll
    for (int m = 0; m < 4; ++m) {
        ushort4 uq = *reinterpret_cast<const ushort4*>(&qkv[base + (size_t)m * 3072]);
        ushort4 uk = *reinterpret_cast<const ushort4*>(&qkv[base + (size_t)m * 3072 + 1024]);
        ushort4 uv = *reinterpret_cast<const ushort4*>(&qkv[base + (size_t)m * 3072 + 2048]);
        q[m][0] = bf2f(uq.x); q[m][1] = bf2f(uq.y); q[m][2] = bf2f(uq.z); q[m][3] = bf2f(uq.w);
        k[m][0] = bf2f(uk.x); k[m][1] = bf2f(uk.y); k[m][2] = bf2f(uk.z); k[m][3] = bf2f(uk.w);
        v[m][0] = bf2f(uv.x); v[m][1] = bf2f(uv.y); v[m][2] = bf2f(uv.z); v[m][3] = bf2f(uv.w);
    }

    float s[4][4];
#pragma unroll
    for (int qi = 0; qi < 4; ++qi)
#pragma unroll
        for (int ki = 0; ki < 4; ++ki)
            s[qi][ki] = q[qi][0] * k[ki][0] + q[qi][1] * k[ki][1] +
                        q[qi][2] * k[ki][2] + q[qi][3] * k[ki][3];
#pragma unroll
    for (int off = 32; off >= 1; off >>= 1) {
#pragma unroll
        for (int qi = 0; qi < 4; ++qi)
#pragma unroll
            for (int ki = 0; ki < 4; ++ki)
                s[qi][ki] += __shfl_xor(s[qi][ki], off, 64);
    }

#pragma unroll
    for (int qi = 0; qi < 4; ++qi) {
        float s0 = s[qi][0] * 0.0625f, s1 = s[qi][1] * 0.0625f;
        float s2 = s[qi][2] * 0.0625f, s3 = s[qi][3] * 0.0625f;
        float mx = fmaxf(fmaxf(s0, s1), fmaxf(s2, s3));
        float e0 = __expf(s0 - mx), e1 = __expf(s1 - mx);
        float e2 = __expf(s2 - mx), e3 = __expf(s3 - mx);
        float inv = 1.0f / (e0 + e1 + e2 + e3);
        e0 *= inv; e1 *= inv; e2 *= inv; e3 *= inv;
        ushort4 o;
        o.x = f2bf(e0 * v[0][0] + e1 * v[1][0] + e2 * v[2][0] + e3 * v[3][0]);
        o.y = f2bf(e0 * v[0][1] + e1 * v[1][1] + e2 * v[2][1] + e3 * v[3][1]);
        o.z = f2bf(e0 * v[0][2] + e1 * v[1][2] + e2 * v[2][2] + e3 * v[3][2]);
        o.w = f2bf(e0 * v[0][3] + e1 * v[1][3] + e2 * v[2][3] + e3 * v[3][3]);
        *reinterpret_cast<ushort4*>(&ctx[(size_t)(n * 4 + qi) * 1024 + h * HD + lane * 4]) = o;
    }
}

// ---------------- residual + LayerNorm ----------------
__global__ void resid_ln(const float* __restrict__ cons, const float* __restrict__ feat,
                         const float* __restrict__ g, const float* __restrict__ b,
                         float* __restrict__ out) {
    const int row = blockIdx.x;
    const int t = threadIdx.x;
    const size_t base = (size_t)row * DM + t * 4;
    float4 c = *reinterpret_cast<const float4*>(&cons[base]);
    float4 f = *reinterpret_cast<const float4*>(&feat[base]);
    float y0 = c.x + f.x, y1 = c.y + f.y, y2 = c.z + f.z, y3 = c.w + f.w;
    float sum = y0 + y1 + y2 + y3;
    float sq = y0 * y0 + y1 * y1 + y2 * y2 + y3 * y3;
#pragma unroll
    for (int off = 32; off >= 1; off >>= 1) {
        sum += __shfl_xor(sum, off, 64);
        sq += __shfl_xor(sq, off, 64);
    }
    __shared__ float rs[4], rq[4];
    const int wv = t >> 6, ln = t & 63;
    if (ln == 0) { rs[wv] = sum; rq[wv] = sq; }
    __syncthreads();
    sum = rs[0] + rs[1] + rs[2] + rs[3];
    sq = rq[0] + rq[1] + rq[2] + rq[3];
    const float mu = sum * (1.0f / DM);
    const float var = sq * (1.0f / DM) - mu * mu;
    const float rstd = rsqrtf(var + 1e-5f);
    float4 gg = *reinterpret_cast<const float4*>(&g[t * 4]);
    float4 bb = *reinterpret_cast<const float4*>(&b[t * 4]);
    float4 o;
    o.x = (y0 - mu) * rstd * gg.x + bb.x;
    o.y = (y1 - mu) * rstd * gg.y + bb.y;
    o.z = (y2 - mu) * rstd * gg.z + bb.z;
    o.w = (y3 - mu) * rstd * gg.w + bb.w;
    *reinterpret_cast<float4*>(&out[base]) = o;
}

// ---------------- launch ----------------
extern "C" void kernel_launch(void* const* d_in, const int* in_sizes, int n_in,
                              void* d_out, int out_size, void* d_ws, size_t ws_size,
                              hipStream_t stream) {
    (void)in_sizes; (void)n_in; (void)out_size;
    const float* feat = (const float*)d_in[0];
    const int* am = (const int*)d_in[1];
    const int* dmk = (const int*)d_in[2];
    const int* em = (const int*)d_in[3];
    const int* hmk = (const int*)d_in[4];
    const float* Wa = (const float*)d_in[5];  const float* ba = (const float*)d_in[6];
    const float* Wd = (const float*)d_in[7];  const float* bd = (const float*)d_in[8];
    const float* We = (const float*)d_in[9];  const float* be = (const float*)d_in[10];
    const float* Wh = (const float*)d_in[11]; const float* bh = (const float*)d_in[12];
    const float* Wq = (const float*)d_in[13]; const float* bq = (const float*)d_in[14];
    const float* Wk = (const float*)d_in[15]; const float* bk = (const float*)d_in[16];
    const float* Wv = (const float*)d_in[17]; const float* bv = (const float*)d_in[18];
    const float* Wo = (const float*)d_in[19]; const float* bo = (const float*)d_in[20];
    const float* Wg1 = (const float*)d_in[21]; const float* bg1 = (const float*)d_in[22];
    const float* Wg2 = (const float*)d_in[23]; const float* bg2 = (const float*)d_in[24];
    const float* lng = (const float*)d_in[25]; const float* lnb = (const float*)d_in[26];

    hipFuncSetAttribute(reinterpret_cast<const void*>(&gemm_bt8<0>),
                        hipFuncAttributeMaxDynamicSharedMemorySize, 131072);
    hipFuncSetAttribute(reinterpret_cast<const void*>(&gemm_bt8<1>),
                        hipFuncAttributeMaxDynamicSharedMemorySize, 131072);
    hipFuncSetAttribute(reinterpret_cast<const void*>(&gemm_bt8<2>),
                        hipFuncAttributeMaxDynamicSharedMemorySize, 131072);

    char* ws = (char*)d_ws;
    size_t off = 0;
    auto take = [&](size_t bytes) -> char* {
        char* r = ws + off;
        off = (off + bytes + 255) & ~(size_t)255;
        return r;
    };
    // ---- fixed weight/feature allocations: ~54.6 MB ----
    unsigned short* featB = (unsigned short*)take((size_t)NT * DM * 2);
    unsigned short* Bt1   = (unsigned short*)take((size_t)4 * DM * DM * 2);
    unsigned short* Btqkv = (unsigned short*)take((size_t)3 * DM * DM * 2);
    unsigned short* Bto   = (unsigned short*)take((size_t)DM * DM * 2);
    unsigned short* Btg1  = (unsigned short*)take((size_t)2 * DM * 4 * DM * 2);
    unsigned short* Btg2  = (unsigned short*)take((size_t)DM * 2 * DM * 2);
    const size_t fixed = off;

    cvt_f32_to_bf16<<<dim3((NT * DM / 4 + 255) / 256), dim3(256), 0, stream>>>(
        feat, featB, NT * DM / 4);
    auto tl = [&](const float* src, unsigned short* dst, int K, int Nc) {
        transpose_cvt<<<dim3(Nc / 32, K / 32), dim3(256), 0, stream>>>(src, dst, K, Nc);
    };
    tl(Wa, Bt1, DM, DM);
    tl(Wd, Bt1 + (size_t)DM * DM, DM, DM);
    tl(We, Bt1 + (size_t)2 * DM * DM, DM, DM);
    tl(Wh, Bt1 + (size_t)3 * DM * DM, DM, DM);
    tl(Wq, Btqkv, DM, DM);
    tl(Wk, Btqkv + (size_t)DM * DM, DM, DM);
    tl(Wv, Btqkv + (size_t)2 * DM * DM, DM, DM);
    tl(Wo, Bto, DM, DM);
    tl(Wg1, Btg1, 4 * DM, 2 * DM);
    tl(Wg2, Btg2, 2 * DM, DM);

    Ptr4 b1{{ba, bd, be, bh}};
    Ptr4 bqkv{{bq, bk, bv, nullptr}};
    Ptr4 bo4{{bo, nullptr, nullptr, nullptr}};
    Ptr4 bg14{{bg1, bg1 + DM, nullptr, nullptr}};
    Ptr4 bg24{{bg2, nullptr, nullptr, nullptr}};
    Mask4 mnull{{nullptr, nullptr, nullptr, nullptr}};
    Mask4 mkAll{{am, dmk, em, hmk}};

    // ---- plan B: full-size GEMMs (256^2 deep-pipe), chunk only attention path ----
    const size_t xBytes = (size_t)NT * 4096 * 2;
    const size_t hBytes = (size_t)NT * 2048 * 2 + 512;
    int T2 = 0;
    {
        const int cands[4] = {8192, 4096, 2048, 1024};
        for (int ci = 0; ci < 4; ++ci) {
            int c = cands[ci];
            size_t chunkB = (size_t)c * 24576 + 512 + (size_t)c * 8192;
            size_t regHB = chunkB > hBytes ? chunkB : hBytes;
            if (fixed + xBytes + 256 + regHB + 4096 <= ws_size) { T2 = c; break; }
        }
    }

    if (T2 > 0) {
        char* regX = take(xBytes);
        size_t chunkB = (size_t)T2 * 24576 + 512 + (size_t)T2 * 8192;
        char* regH = take(chunkB > hBytes ? chunkB : hBytes);
        unsigned short* x = (unsigned short*)regX;      // x / attended (bf16)
        float* cons = (float*)regX;                     // consensus (f32)
        unsigned short* h = (unsigned short*)regH;
        unsigned short* qkv_c = (unsigned short*)regH;
        unsigned short* ctx_c = (unsigned short*)(regH + (size_t)T2 * 24576 + 512);

        // 1) masked modality projections: x[NT][4096]
        gemm_bt8<0><<<dim3(16, NT / 256), dim3(512), 131072, stream>>>(
            featB, Bt1, (void*)x, b1, mkAll, NT, 4 * DM, DM);
        // 2-4) attention path, chunked
        for (int t0 = 0; t0 < NT; t0 += T2) {
            unsigned short* xc = x + (size_t)t0 * 4096;
            gemm_bt8<1><<<dim3(12, 4 * T2 / 256), dim3(512), 131072, stream>>>(
                xc, Btqkv, (void*)qkv_c, bqkv, mnull, 4 * T2, 3 * DM, DM);
            attn4<<<dim3(T2), dim3(256), 0, stream>>>(qkv_c, ctx_c);
            gemm_bt8<1><<<dim3(4, 4 * T2 / 256), dim3(512), 131072, stream>>>(
                ctx_c, Bto, (void*)xc, bo4, mnull, 4 * T2, DM, DM);
        }
        // 5) gate MLP1 (+GELU): h[NT][2048]
        gemm_bt8<2><<<dim3(8, NT / 256), dim3(512), 131072, stream>>>(
            x, Btg1, (void*)h, bg14, mnull, NT, 2 * DM, 4 * DM);
        // 6) gate MLP2: cons f32 [NT][1024]
        gemm_bt<3><<<dim3(8, NT / BM), dim3(256), 0, stream>>>(
            h, Btg2, (void*)cons, bg24, mnull, NT, DM, 2 * DM);
        // 7) residual + LayerNorm
        resid_ln<<<dim3(NT), dim3(256), 0, stream>>>(cons, feat, lng, lnb, (float*)d_out);
        return;
    }

    // ---- plan A fallback (known-good fully-chunked 128^2 pipeline) ----
    const size_t avail = (ws_size > fixed) ? (ws_size - fixed) : 0;
    int T = 2048;
    while (T > 128 && ((size_t)T * 40960 + 4096) > avail) T >>= 1;
    unsigned short* bufA = (unsigned short*)take((size_t)T * 4096 * 2);
    unsigned short* bufB = (unsigned short*)take((size_t)T * 4 * 3072 * 2);
    unsigned short* bufC = (unsigned short*)take((size_t)T * 4 * 1024 * 2);

    const int nch = NT / T;
    for (int c = 0; c < nch; ++c) {
        const int t0 = c * T;
        Mask4 mk{{am + t0, dmk + t0, em + t0, hmk + t0}};
        gemm_bt<0><<<dim3(4 * DM / BN, T / BM), dim3(256), 0, stream>>>(
            featB + (size_t)t0 * DM, Bt1, (void*)bufA, b1, mk, T, 4 * DM, DM);
        gemm_bt<1><<<dim3(3 * DM / BN, 4 * T / BM), dim3(256), 0, stream>>>(
            bufA, Btqkv, (void*)bufB, bqkv, mnull, 4 * T, 3 * DM, DM);
        attn4<<<dim3(T), dim3(256), 0, stream>>>(bufB, bufC);
        gemm_bt<1><<<dim3(DM / BN, 4 * T / BM), dim3(256), 0, stream>>>(
            bufC, Bto, (void*)bufA, bo4, mnull, 4 * T, DM, DM);
        gemm_bt<2><<<dim3(2 * DM / BN, T / BM), dim3(256), 0, stream>>>(
            bufA, Btg1, (void*)bufC, bg14, mnull, T, 2 * DM, 4 * DM);
        gemm_bt<3><<<dim3(DM / BN, T / BM), dim3(256), 0, stream>>>(
            bufC, Btg2, (void*)bufB, bg24, mnull, T, DM, 2 * DM);
        resid_ln<<<dim3(T), dim3(256), 0, stream>>>(
            (const float*)bufB, feat + (size_t)t0 * DM, lng, lnb,
            (float*)d_out + (size_t)t0 * DM);
    }
}

// Round 7
// 696.055 us; speedup vs baseline: 1.5689x; 1.0129x over previous
//
#include <hip/hip_runtime.h>
#include <cstdint>
#include <cstddef>

// ---------------- constants ----------------
#define DM   1024          // model dim
#define NT   8192          // B*L tokens
#define HD   256
#define BM 128
#define BN 128
#define BK 32

typedef __attribute__((ext_vector_type(4))) float f32x4;
typedef __attribute__((ext_vector_type(8))) short bf16x8;

#define MF(a_, b_, c_) __builtin_amdgcn_mfma_f32_16x16x32_bf16(a_, b_, c_, 0, 0, 0)

__device__ __forceinline__ unsigned short f2bf(float f) {
    union { float f; uint32_t u; } v; v.f = f;
    return (unsigned short)((v.u + 0x7fffu + ((v.u >> 16) & 1u)) >> 16);
}
__device__ __forceinline__ float bf2f(unsigned short h) {
    union { uint32_t u; float f; } v; v.u = ((uint32_t)h) << 16;
    return v.f;
}

// T1: XCD-chunked bijective blockIdx swizzle (bijective when nwg%8==0).
__device__ __forceinline__ int2 xcd_swizzle_xy() {
    int wid = blockIdx.y * gridDim.x + blockIdx.x;
    const int nwg = gridDim.x * gridDim.y;
    if ((nwg & 7) == 0) {
        const int per = nwg >> 3;
        wid = (wid & 7) * per + (wid >> 3);
    }
    int2 r;
    r.x = wid % gridDim.x;
    r.y = wid / gridDim.x;
    return r;
}

struct Ptr4 { const float* p[4]; };
struct Mask4 { const int* p[4]; };

// ---------------- prep kernels ----------------
__global__ void cvt_f32_to_bf16(const float* __restrict__ src,
                                unsigned short* __restrict__ dst, int n4) {
    int i = blockIdx.x * blockDim.x + threadIdx.x;
    if (i >= n4) return;
    float4 v = reinterpret_cast<const float4*>(src)[i];
    ushort4 o;
    o.x = f2bf(v.x); o.y = f2bf(v.y); o.z = f2bf(v.z); o.w = f2bf(v.w);
    reinterpret_cast<ushort4*>(dst)[i] = o;
}

// src fp32 [K][Nc] row-major  ->  dst bf16 [Nc][K] row-major (transposed)
__global__ void transpose_cvt(const float* __restrict__ src,
                              unsigned short* __restrict__ dst, int K, int Nc) {
    __shared__ float tile[32][33];
    const int n0 = blockIdx.x * 32, k0 = blockIdx.y * 32;
    const int tx = threadIdx.x & 31, ty = threadIdx.x >> 5;   // 32 x 8
#pragma unroll
    for (int i = 0; i < 4; ++i) {
        int k = ty + i * 8;
        tile[k][tx] = src[(size_t)(k0 + k) * Nc + n0 + tx];
    }
    __syncthreads();
#pragma unroll
    for (int i = 0; i < 4; ++i) {
        int n = ty + i * 8;
        dst[(size_t)(n0 + n) * K + k0 + tx] = f2bf(tile[tx][n]);
    }
}

__device__ __forceinline__ void gload16(const void* g, void* l) {
    __builtin_amdgcn_global_load_lds(
        (const __attribute__((address_space(1))) void*)g,
        (__attribute__((address_space(3))) void*)l, 16, 0, 0);
}

// ---------------- 128x128 GEMM: C[M][Nc] = A[M][K] x Bt[Nc][K]^T ----------------
// EPI: 0=(acc+bias)*mask->bf16            (legacy modality projection, plan A)
//      1=acc+bias->bf16                   (plan A)
//      2=gelu(acc+bias)->bf16             (MLP1)
//      3=acc+bias->f32                    (MLP2)
//      5=mask*(acc+biasA[col])+bias2->bf16 (fused QKV; col layout qk*4096+i*1024+j)
template <int EPI>
__global__ void gemm_bt(const unsigned short* __restrict__ A,
                        const unsigned short* __restrict__ Bt,
                        void* __restrict__ out, Ptr4 bias, Mask4 masks,
                        const float* __restrict__ biasA,
                        int M, int Nc, int K) {
    __shared__ __attribute__((aligned(16))) unsigned short Als[BM * BK];
    __shared__ __attribute__((aligned(16))) unsigned short Bls[BN * BK];
    const int tid = threadIdx.x;
    const int wave = tid >> 6, lane = tid & 63;
    const int2 bxy = xcd_swizzle_xy();
    const int tileM = bxy.y * BM, tileN = bxy.x * BN;
    const int wr = wave >> 1, wc = wave & 1;

    f32x4 acc[4][4] = {};

    const int sr = tid >> 2;
    const int sc = (tid & 3) * 8;
    const unsigned short* aSrc0 = A + (size_t)(tileM + sr) * K + sc;
    const unsigned short* aSrc1 = A + (size_t)(tileM + 64 + sr) * K + sc;
    const unsigned short* bSrc0 = Bt + (size_t)(tileN + sr) * K + sc;
    const unsigned short* bSrc1 = Bt + (size_t)(tileN + 64 + sr) * K + sc;
    unsigned short* aDst0 = &Als[wave * 512];
    unsigned short* aDst1 = &Als[2048 + wave * 512];
    unsigned short* bDst0 = &Bls[wave * 512];
    unsigned short* bDst1 = &Bls[2048 + wave * 512];

    const int la = lane & 15;
    const int lb = (lane >> 4) * 8;

    for (int k0 = 0; k0 < K; k0 += BK) {
        gload16(aSrc0 + k0, aDst0);
        gload16(aSrc1 + k0, aDst1);
        gload16(bSrc0 + k0, bDst0);
        gload16(bSrc1 + k0, bDst1);
        __syncthreads();
        bf16x8 af[4], bfr[4];
#pragma unroll
        for (int m = 0; m < 4; ++m)
            af[m] = *reinterpret_cast<const bf16x8*>(&Als[(wr * 64 + m * 16 + la) * BK + lb]);
#pragma unroll
        for (int n = 0; n < 4; ++n)
            bfr[n] = *reinterpret_cast<const bf16x8*>(&Bls[(wc * 64 + n * 16 + la) * BK + lb]);
#pragma unroll
        for (int m = 0; m < 4; ++m)
#pragma unroll
            for (int n = 0; n < 4; ++n)
                acc[m][n] = MF(af[m], bfr[n], acc[m][n]);
        __syncthreads();
    }

    const int rowT = tileM + wr * 64 + (lane >> 4) * 4;
    const int colT = tileN + wc * 64;
    unsigned short* outB = (unsigned short*)out;
    float* outF = (float*)out;

    float mv[4][4];
    if constexpr (EPI == 0 || EPI == 5) {
        const int* mp = (EPI == 0) ? masks.p[tileN >> 10] : masks.p[(tileN >> 10) & 3];
#pragma unroll
        for (int m = 0; m < 4; ++m)
#pragma unroll
            for (int i = 0; i < 4; ++i)
                mv[m][i] = (float)mp[rowT + m * 16 + i];
    }
    const float* bp = nullptr;
    const float* bp2 = nullptr;
    if constexpr (EPI == 5) bp2 = bias.p[tileN >> 12];
    else bp = bias.p[tileN >> 10];

#pragma unroll
    for (int n = 0; n < 4; ++n) {
        const int gcol = colT + n * 16 + la;
        float bv, bv2 = 0.f;
        if constexpr (EPI == 5) { bv = biasA[gcol]; bv2 = bp2[gcol & (DM - 1)]; }
        else bv = bp[gcol & (DM - 1)];
#pragma unroll
        for (int m = 0; m < 4; ++m) {
#pragma unroll
            for (int i = 0; i < 4; ++i) {
                const int grow = rowT + m * 16 + i;
                float val = acc[m][n][i] + bv;
                if constexpr (EPI == 0) {
                    val *= mv[m][i];
                    outB[(size_t)grow * Nc + gcol] = f2bf(val);
                } else if constexpr (EPI == 1) {
                    outB[(size_t)grow * Nc + gcol] = f2bf(val);
                } else if constexpr (EPI == 2) {
                    val = 0.5f * val * (1.0f + erff(val * 0.70710678118654752f));
                    outB[(size_t)grow * Nc + gcol] = f2bf(val);
                } else if constexpr (EPI == 3) {
                    outF[(size_t)grow * Nc + gcol] = val;
                } else { // EPI == 5
                    val = mv[m][i] * val + bv2;
                    outB[(size_t)grow * Nc + gcol] = f2bf(val);
                }
            }
        }
    }
}

// ---------------- weight-fusion prep GEMM (128^2 core, strided) ----------------
// TSTORE=true  (P1): A=Wcat[(i,k),t], Bt=Btqkv[(qk,j),t];
//   C[(i,k),(qk,j)] = (W_i @ W_qk)[k,j] stored into Btf[(qk*4096+i*1024+j), k].
// TSTORE=false (P2): per-z slice: A=Btg1[:, z*1024+t] (lda=4096), Bt=Wo_bf[k,t];
//   C[c,k] = (Wo@Wg1_z)^T stored at out[c*ldc + z*cZstride + k].
template <bool TSTORE>
__global__ void gemm_prep(const unsigned short* __restrict__ A0, int lda, int aZoff,
                          const unsigned short* __restrict__ Bt, int ldb,
                          unsigned short* __restrict__ out, int ldc, int cZstride,
                          int K) {
    __shared__ __attribute__((aligned(16))) unsigned short Als[BM * BK];
    __shared__ __attribute__((aligned(16))) unsigned short Bls[BN * BK];
    const unsigned short* A = A0 + (size_t)blockIdx.z * aZoff;
    const int tid = threadIdx.x;
    const int wave = tid >> 6, lane = tid & 63;
    const int2 bxy = xcd_swizzle_xy();
    const int tileM = bxy.y * BM, tileN = bxy.x * BN;
    const int wr = wave >> 1, wc = wave & 1;

    f32x4 acc[4][4] = {};

    const int sr = tid >> 2;
    const int sc = (tid & 3) * 8;
    const unsigned short* aSrc0 = A + (size_t)(tileM + sr) * lda + sc;
    const unsigned short* aSrc1 = A + (size_t)(tileM + 64 + sr) * lda + sc;
    const unsigned short* bSrc0 = Bt + (size_t)(tileN + sr) * ldb + sc;
    const unsigned short* bSrc1 = Bt + (size_t)(tileN + 64 + sr) * ldb + sc;
    unsigned short* aDst0 = &Als[wave * 512];
    unsigned short* aDst1 = &Als[2048 + wave * 512];
    unsigned short* bDst0 = &Bls[wave * 512];
    unsigned short* bDst1 = &Bls[2048 + wave * 512];

    const int la = lane & 15;
    const int lb = (lane >> 4) * 8;

    for (int k0 = 0; k0 < K; k0 += BK) {
        gload16(aSrc0 + k0, aDst0);
        gload16(aSrc1 + k0, aDst1);
        gload16(bSrc0 + k0, bDst0);
        gload16(bSrc1 + k0, bDst1);
        __syncthreads();
        bf16x8 af[4], bfr[4];
#pragma unroll
        for (int m = 0; m < 4; ++m)
            af[m] = *reinterpret_cast<const bf16x8*>(&Als[(wr * 64 + m * 16 + la) * BK + lb]);
#pragma unroll
        for (int n = 0; n < 4; ++n)
            bfr[n] = *reinterpret_cast<const bf16x8*>(&Bls[(wc * 64 + n * 16 + la) * BK + lb]);
#pragma unroll
        for (int m = 0; m < 4; ++m)
#pragma unroll
            for (int n = 0; n < 4; ++n)
                acc[m][n] = MF(af[m], bfr[n], acc[m][n]);
        __syncthreads();
    }

    const int rowT = tileM + wr * 64 + (lane >> 4) * 4;
    const int colT = tileN + wc * 64;

#pragma unroll
    for (int n = 0; n < 4; ++n) {
        const int gcol = colT + n * 16 + la;
#pragma unroll
        for (int m = 0; m < 4; ++m) {
            if constexpr (TSTORE) {
                const int g0 = rowT + m * 16;          // (i,k): i=g0>>10, k=g0&1023
                ushort4 o4;
                o4.x = f2bf(acc[m][n][0]);
                o4.y = f2bf(acc[m][n][1]);
                o4.z = f2bf(acc[m][n][2]);
                o4.w = f2bf(acc[m][n][3]);
                const size_t drow = ((size_t)(gcol >> 10) << 12) +
                                    ((size_t)(g0 >> 10) << 10) + (gcol & 1023);
                *reinterpret_cast<ushort4*>(out + drow * 1024 + (g0 & 1023)) = o4;
            } else {
#pragma unroll
                for (int i = 0; i < 4; ++i) {
                    const int grow = rowT + m * 16 + i;
                    out[(size_t)grow * ldc + (size_t)blockIdx.z * cZstride + gcol] =
                        f2bf(acc[m][n][i]);
                }
            }
        }
    }
}

// ---------------- bias folding ----------------
// biasA[qk*4096+i*1024+j] = (b_i @ W_qk)[j]  (one wave per output)
__global__ void fuse_biasA(Ptr4 bmods, const unsigned short* __restrict__ Btqkv,
                           float* __restrict__ biasA) {
    const int o = blockIdx.x * 4 + (threadIdx.x >> 6);
    const int lane = threadIdx.x & 63;
    const int qk = o >> 12, im = (o >> 10) & 3, j = o & 1023;
    const float* b = bmods.p[im];
    const unsigned short* wrow = Btqkv + ((size_t)(qk << 10) + j) * 1024;
    float s = 0.f;
    for (int t = lane; t < 1024; t += 64) s += b[t] * bf2f(wrow[t]);
#pragma unroll
    for (int off = 32; off >= 1; off >>= 1) s += __shfl_xor(s, off, 64);
    if (lane == 0) biasA[o] = s;
}

// biasH[c] = bg1[c] + sum_t bo[t&1023] * Wg1stack  (via Btg1 row c)
__global__ void fuse_biasH(const float* __restrict__ bo, const float* __restrict__ bg1,
                           const unsigned short* __restrict__ Btg1,
                           float* __restrict__ biasH) {
    const int c = blockIdx.x * 4 + (threadIdx.x >> 6);
    const int lane = threadIdx.x & 63;
    const unsigned short* row = Btg1 + (size_t)c * 4096;
    float s = 0.f;
    for (int t = lane; t < 4096; t += 64) s += bo[t & 1023] * bf2f(row[t]);
#pragma unroll
    for (int off = 32; off >= 1; off >>= 1) s += __shfl_xor(s, off, 64);
    if (lane == 0) biasH[c] = s + bg1[c];
}

// ---------------- tiny 4-token attention, fused-QKV layout ----------------
// qkvF bf16 [T][12288]: col = qk*4096 + i*1024 + j; ctx bf16 [T][4096]
__global__ void attn4F(const unsigned short* __restrict__ qkvF,
                       unsigned short* __restrict__ ctx) {
    const int n = blockIdx.x;
    const int h = threadIdx.x >> 6;
    const int lane = threadIdx.x & 63;
    const size_t base = (size_t)n * 12288 + h * HD + lane * 4;

    float q[4][4], k[4][4], v[4][4];
#pragma unroll
    for (int m = 0; m < 4; ++m) {
        ushort4 uq = *reinterpret_cast<const ushort4*>(&qkvF[base + m * 1024]);
        ushort4 uk = *reinterpret_cast<const ushort4*>(&qkvF[base + m * 1024 + 4096]);
        ushort4 uv = *reinterpret_cast<const ushort4*>(&qkvF[base + m * 1024 + 8192]);
        q[m][0] = bf2f(uq.x); q[m][1] = bf2f(uq.y); q[m][2] = bf2f(uq.z); q[m][3] = bf2f(uq.w);
        k[m][0] = bf2f(uk.x); k[m][1] = bf2f(uk.y); k[m][2] = bf2f(uk.z); k[m][3] = bf2f(uk.w);
        v[m][0] = bf2f(uv.x); v[m][1] = bf2f(uv.y); v[m][2] = bf2f(uv.z); v[m][3] = bf2f(uv.w);
    }

    float s[4][4];
#pragma unroll
    for (int qi = 0; qi < 4; ++qi)
#pragma unroll
        for (int ki = 0; ki < 4; ++ki)
            s[qi][ki] = q[qi][0] * k[ki][0] + q[qi][1] * k[ki][1] +
                        q[qi][2] * k[ki][2] + q[qi][3] * k[ki][3];
#pragma unroll
    for (int off = 32; off >= 1; off >>= 1) {
#pragma unroll
        for (int qi = 0; qi < 4; ++qi)
#pragma unroll
            for (int ki = 0; ki < 4; ++ki)
                s[qi][ki] += __shfl_xor(s[qi][ki], off, 64);
    }

#pragma unroll
    for (int qi = 0; qi < 4; ++qi) {
        float s0 = s[qi][0] * 0.0625f, s1 = s[qi][1] * 0.0625f;
        float s2 = s[qi][2] * 0.0625f, s3 = s[qi][3] * 0.0625f;
        float mx = fmaxf(fmaxf(s0, s1), fmaxf(s2, s3));
        float e0 = __expf(s0 - mx), e1 = __expf(s1 - mx);
        float e2 = __expf(s2 - mx), e3 = __expf(s3 - mx);
        float inv = 1.0f / (e0 + e1 + e2 + e3);
        e0 *= inv; e1 *= inv; e2 *= inv; e3 *= inv;
        ushort4 o;
        o.x = f2bf(e0 * v[0][0] + e1 * v[1][0] + e2 * v[2][0] + e3 * v[3][0]);
        o.y = f2bf(e0 * v[0][1] + e1 * v[1][1] + e2 * v[2][1] + e3 * v[3][1]);
        o.z = f2bf(e0 * v[0][2] + e1 * v[1][2] + e2 * v[2][2] + e3 * v[3][2]);
        o.w = f2bf(e0 * v[0][3] + e1 * v[1][3] + e2 * v[2][3] + e3 * v[3][3]);
        *reinterpret_cast<ushort4*>(&ctx[(size_t)n * 4096 + qi * 1024 + h * HD + lane * 4]) = o;
    }
}

// ---------------- tiny 4-token attention, legacy layout (plan A) ----------------
__global__ void attn4(const unsigned short* __restrict__ qkv,
                      unsigned short* __restrict__ ctx) {
    const int n = blockIdx.x;
    const int h = threadIdx.x >> 6;
    const int lane = threadIdx.x & 63;
    const size_t base = (size_t)n * 4 * 3072 + h * HD + lane * 4;

    float q[4][4], k[4][4], v[4][4];
#pragma unroll
    for (int m = 0; m < 4; ++m) {
        ushort4 uq = *reinterpret_cast<const ushort4*>(&qkv[base + (size_t)m * 3072]);
        ushort4 uk = *reinterpret_cast<const ushort4*>(&qkv[base + (size_t)m * 3072 + 1024]);
        ushort4 uv = *reinterpret_cast<const ushort4*>(&qkv[base + (size_t)m * 3072 + 2048]);
        q[m][0] = bf2f(uq.x); q[m][1] = bf2f(uq.y); q[m][2] = bf2f(uq.z); q[m][3] = bf2f(uq.w);
        k[m][0] = bf2f(uk.x); k[m][1] = bf2f(uk.y); k[m][2] = bf2f(uk.z); k[m][3] = bf2f(uk.w);
        v[m][0] = bf2f(uv.x); v[m][1] = bf2f(uv.y); v[m][2] = bf2f(uv.z); v[m][3] = bf2f(uv.w);
    }

    float s[4][4];
#pragma unroll
    for (int qi = 0; qi < 4; ++qi)
#pragma unroll
        for (int ki = 0; ki < 4; ++ki)
            s[qi][ki] = q[qi][0] * k[ki][0] + q[qi][1] * k[ki][1] +
                        q[qi][2] * k[ki][2] + q[qi][3] * k[ki][3];
#pragma unroll
    for (int off = 32; off >= 1; off >>= 1) {
#pragma unroll
        for (int qi = 0; qi < 4; ++qi)
#pragma unroll
            for (int ki = 0; ki < 4; ++ki)
                s[qi][ki] += __shfl_xor(s[qi][ki], off, 64);
    }

#pragma unroll
    for (int qi = 0; qi < 4; ++qi) {
        float s0 = s[qi][0] * 0.0625f, s1 = s[qi][1] * 0.0625f;
        float s2 = s[qi][2] * 0.0625f, s3 = s[qi][3] * 0.0625f;
        float mx = fmaxf(fmaxf(s0, s1), fmaxf(s2, s3));
        float e0 = __expf(s0 - mx), e1 = __expf(s1 - mx);
        float e2 = __expf(s2 - mx), e3 = __expf(s3 - mx);
        float inv = 1.0f / (e0 + e1 + e2 + e3);
        e0 *= inv; e1 *= inv; e2 *= inv; e3 *= inv;
        ushort4 o;
        o.x = f2bf(e0 * v[0][0] + e1 * v[1][0] + e2 * v[2][0] + e3 * v[3][0]);
        o.y = f2bf(e0 * v[0][1] + e1 * v[1][1] + e2 * v[2][1] + e3 * v[3][1]);
        o.z = f2bf(e0 * v[0][2] + e1 * v[1][2] + e2 * v[2][2] + e3 * v[3][2]);
        o.w = f2bf(e0 * v[0][3] + e1 * v[1][3] + e2 * v[2][3] + e3 * v[3][3]);
        *reinterpret_cast<ushort4*>(&ctx[(size_t)(n * 4 + qi) * 1024 + h * HD + lane * 4]) = o;
    }
}

// ---------------- residual + LayerNorm ----------------
__global__ void resid_ln(const float* __restrict__ cons, const float* __restrict__ feat,
                         const float* __restrict__ g, const float* __restrict__ b,
                         float* __restrict__ out) {
    const int row = blockIdx.x;
    const int t = threadIdx.x;
    const size_t base = (size_t)row * DM + t * 4;
    float4 c = *reinterpret_cast<const float4*>(&cons[base]);
    float4 f = *reinterpret_cast<const float4*>(&feat[base]);
    float y0 = c.x + f.x, y1 = c.y + f.y, y2 = c.z + f.z, y3 = c.w + f.w;
    float sum = y0 + y1 + y2 + y3;
    float sq = y0 * y0 + y1 * y1 + y2 * y2 + y3 * y3;
#pragma unroll
    for (int off = 32; off >= 1; off >>= 1) {
        sum += __shfl_xor(sum, off, 64);
        sq += __shfl_xor(sq, off, 64);
    }
    __shared__ float rs[4], rq[4];
    const int wv = t >> 6, ln = t & 63;
    if (ln == 0) { rs[wv] = sum; rq[wv] = sq; }
    __syncthreads();
    sum = rs[0] + rs[1] + rs[2] + rs[3];
    sq = rq[0] + rq[1] + rq[2] + rq[3];
    const float mu = sum * (1.0f / DM);
    const float var = sq * (1.0f / DM) - mu * mu;
    const float rstd = rsqrtf(var + 1e-5f);
    float4 gg = *reinterpret_cast<const float4*>(&g[t * 4]);
    float4 bb = *reinterpret_cast<const float4*>(&b[t * 4]);
    float4 o;
    o.x = (y0 - mu) * rstd * gg.x + bb.x;
    o.y = (y1 - mu) * rstd * gg.y + bb.y;
    o.z = (y2 - mu) * rstd * gg.z + bb.z;
    o.w = (y3 - mu) * rstd * gg.w + bb.w;
    *reinterpret_cast<float4*>(&out[base]) = o;
}

// ---------------- launch ----------------
extern "C" void kernel_launch(void* const* d_in, const int* in_sizes, int n_in,
                              void* d_out, int out_size, void* d_ws, size_t ws_size,
                              hipStream_t stream) {
    (void)in_sizes; (void)n_in; (void)out_size;
    const float* feat = (const float*)d_in[0];
    const int* am = (const int*)d_in[1];
    const int* dmk = (const int*)d_in[2];
    const int* em = (const int*)d_in[3];
    const int* hmk = (const int*)d_in[4];
    const float* Wa = (const float*)d_in[5];  const float* ba = (const float*)d_in[6];
    const float* Wd = (const float*)d_in[7];  const float* bd = (const float*)d_in[8];
    const float* We = (const float*)d_in[9];  const float* be = (const float*)d_in[10];
    const float* Wh = (const float*)d_in[11]; const float* bh = (const float*)d_in[12];
    const float* Wq = (const float*)d_in[13]; const float* bq = (const float*)d_in[14];
    const float* Wk = (const float*)d_in[15]; const float* bk = (const float*)d_in[16];
    const float* Wv = (const float*)d_in[17]; const float* bv = (const float*)d_in[18];
    const float* Wo = (const float*)d_in[19]; const float* bo = (const float*)d_in[20];
    const float* Wg1 = (const float*)d_in[21]; const float* bg1 = (const float*)d_in[22];
    const float* Wg2 = (const float*)d_in[23]; const float* bg2 = (const float*)d_in[24];
    const float* lng = (const float*)d_in[25]; const float* lnb = (const float*)d_in[26];

    char* ws = (char*)d_ws;
    size_t off = 0;
    auto take = [&](size_t bytes) -> char* {
        char* r = ws + off;
        off = (off + bytes + 255) & ~(size_t)255;
        return r;
    };
    // ---- fixed allocations (~97 MB) ----
    unsigned short* featB = (unsigned short*)take((size_t)NT * DM * 2);         // 16.8M
    unsigned short* Btqkv = (unsigned short*)take((size_t)3 * DM * DM * 2);     // 6.3M
    unsigned short* Btg1  = (unsigned short*)take((size_t)2 * DM * 4 * DM * 2); // 16.8M
    unsigned short* Btg2  = (unsigned short*)take((size_t)DM * 2 * DM * 2);     // 4.2M
    unsigned short* Wcat  = (unsigned short*)take((size_t)4 * DM * DM * 2);     // 8.4M
    unsigned short* Wo_bf = (unsigned short*)take((size_t)DM * DM * 2);         // 2.1M
    unsigned short* Btf   = (unsigned short*)take((size_t)12 * DM * DM * 2);    // 25.2M
    unsigned short* Btm1  = (unsigned short*)take((size_t)8 * DM * DM * 2);     // 16.8M
    float* biasA          = (float*)take((size_t)12 * DM * 4);                  // 48K
    float* biasH          = (float*)take((size_t)2 * DM * 4);                   // 8K
    const size_t fixed = off;

    // shared prep
    cvt_f32_to_bf16<<<dim3((NT * DM / 4 + 255) / 256), dim3(256), 0, stream>>>(
        feat, featB, NT * DM / 4);
    auto tl = [&](const float* src, unsigned short* dst, int K, int Nc) {
        transpose_cvt<<<dim3(Nc / 32, K / 32), dim3(256), 0, stream>>>(src, dst, K, Nc);
    };
    tl(Wq, Btqkv, DM, DM);
    tl(Wk, Btqkv + (size_t)DM * DM, DM, DM);
    tl(Wv, Btqkv + (size_t)2 * DM * DM, DM, DM);
    tl(Wg1, Btg1, 4 * DM, 2 * DM);
    tl(Wg2, Btg2, 2 * DM, DM);

    Ptr4 bmods{{ba, bd, be, bh}};
    Ptr4 bqkv{{bq, bk, bv, nullptr}};
    Ptr4 bH{{biasH, biasH + DM, nullptr, nullptr}};
    Ptr4 bg24{{bg2, nullptr, nullptr, nullptr}};
    Mask4 mnull{{nullptr, nullptr, nullptr, nullptr}};

    // ---- plan B sizing: ctx full (67.1M) + qkvF chunk / h (regH) ----
    const size_t ctxBytes = (size_t)NT * 4096 * 2;
    const size_t hBytes = (size_t)NT * 2048 * 2 + 512;
    int T2 = 0;
    {
        const int cands[4] = {8192, 4096, 2048, 1024};
        for (int ci = 0; ci < 4; ++ci) {
            int c = cands[ci];
            size_t chunkB = (size_t)c * 24576 + 512;
            size_t regHB = chunkB > hBytes ? chunkB : hBytes;
            if (fixed + ctxBytes + 256 + regHB + 4096 <= ws_size) { T2 = c; break; }
        }
    }

    if (T2 > 0) {
        char* regX = take(ctxBytes);
        size_t chunkB = (size_t)T2 * 24576 + 512;
        char* regH = take(chunkB > hBytes ? chunkB : hBytes);
        unsigned short* ctx = (unsigned short*)regX;    // ctx bf16 [NT][4096]
        float* cons = (float*)regX;                     // consensus f32 (aliases ctx)
        unsigned short* h = (unsigned short*)regH;      // gelu-h bf16 [NT][2048]
        unsigned short* qkvF = (unsigned short*)regH;   // qkv chunk bf16 [T2][12288]

        // fused-weight prep
        cvt_f32_to_bf16<<<dim3(DM * DM / 4 / 256), dim3(256), 0, stream>>>(Wa, Wcat, DM * DM / 4);
        cvt_f32_to_bf16<<<dim3(DM * DM / 4 / 256), dim3(256), 0, stream>>>(Wd, Wcat + (size_t)DM * DM, DM * DM / 4);
        cvt_f32_to_bf16<<<dim3(DM * DM / 4 / 256), dim3(256), 0, stream>>>(We, Wcat + (size_t)2 * DM * DM, DM * DM / 4);
        cvt_f32_to_bf16<<<dim3(DM * DM / 4 / 256), dim3(256), 0, stream>>>(Wh, Wcat + (size_t)3 * DM * DM, DM * DM / 4);
        cvt_f32_to_bf16<<<dim3(DM * DM / 4 / 256), dim3(256), 0, stream>>>(Wo, Wo_bf, DM * DM / 4);
        // P1: Btf[(qk,i,j),k] = (W_i @ W_qk)[k,j]   M=4096,N=3072,K=1024
        gemm_prep<true><<<dim3(24, 32, 1), dim3(256), 0, stream>>>(
            Wcat, DM, 0, Btqkv, DM, Btf, 0, 0, DM);
        // P2: Btm1[c, i*1024+k] = (Wo @ Wg1_i)^T    M=2048,N=1024,K=1024, z=i
        gemm_prep<false><<<dim3(8, 16, 4), dim3(256), 0, stream>>>(
            Btg1, 4 * DM, DM, Wo_bf, DM, Btm1, 4 * DM, DM, DM);
        fuse_biasA<<<dim3(12 * DM / 4), dim3(256), 0, stream>>>(bmods, Btqkv, biasA);
        fuse_biasH<<<dim3(2 * DM / 4), dim3(256), 0, stream>>>(bo, bg1, Btg1, biasH);

        // fused QKV + attention, chunked over tokens
        for (int t0 = 0; t0 < NT; t0 += T2) {
            Mask4 mk{{am + t0, dmk + t0, em + t0, hmk + t0}};
            gemm_bt<5><<<dim3(96, T2 / BM), dim3(256), 0, stream>>>(
                featB + (size_t)t0 * DM, Btf, (void*)qkvF, bqkv, mk, biasA,
                T2, 12 * DM, DM);
            attn4F<<<dim3(T2), dim3(256), 0, stream>>>(qkvF, ctx + (size_t)t0 * 4096);
        }
        // MLP1 (fused Wo@Wg1) + GELU: h[NT][2048] = gelu(ctx @ Btm1^T + biasH)
        gemm_bt<2><<<dim3(16, NT / BM), dim3(256), 0, stream>>>(
            ctx, Btm1, (void*)h, bH, mnull, nullptr, NT, 2 * DM, 4 * DM);
        // MLP2: cons f32 [NT][1024]
        gemm_bt<3><<<dim3(8, NT / BM), dim3(256), 0, stream>>>(
            h, Btg2, (void*)cons, bg24, mnull, nullptr, NT, DM, 2 * DM);
        // residual + LayerNorm
        resid_ln<<<dim3(NT), dim3(256), 0, stream>>>(cons, feat, lng, lnb, (float*)d_out);
        return;
    }

    // ---- plan A fallback (known-good fully-chunked unfused pipeline) ----
    unsigned short* Bt1 = (unsigned short*)take((size_t)4 * DM * DM * 2);
    unsigned short* Bto = (unsigned short*)take((size_t)DM * DM * 2);
    tl(Wa, Bt1, DM, DM);
    tl(Wd, Bt1 + (size_t)DM * DM, DM, DM);
    tl(We, Bt1 + (size_t)2 * DM * DM, DM, DM);
    tl(Wh, Bt1 + (size_t)3 * DM * DM, DM, DM);
    tl(Wo, Bto, DM, DM);

    Ptr4 b1{{ba, bd, be, bh}};
    Ptr4 bo4{{bo, nullptr, nullptr, nullptr}};
    Ptr4 bg14{{bg1, bg1 + DM, nullptr, nullptr}};

    const size_t avail = (ws_size > off) ? (ws_size - off) : 0;
    int T = 2048;
    while (T > 128 && ((size_t)T * 40960 + 4096) > avail) T >>= 1;
    unsigned short* bufA = (unsigned short*)take((size_t)T * 4096 * 2);
    unsigned short* bufB = (unsigned short*)take((size_t)T * 4 * 3072 * 2);
    unsigned short* bufC = (unsigned short*)take((size_t)T * 4 * 1024 * 2);

    const int nch = NT / T;
    for (int c = 0; c < nch; ++c) {
        const int t0 = c * T;
        Mask4 mk{{am + t0, dmk + t0, em + t0, hmk + t0}};
        gemm_bt<0><<<dim3(4 * DM / BN, T / BM), dim3(256), 0, stream>>>(
            featB + (size_t)t0 * DM, Bt1, (void*)bufA, b1, mk, nullptr, T, 4 * DM, DM);
        gemm_bt<1><<<dim3(3 * DM / BN, 4 * T / BM), dim3(256), 0, stream>>>(
            bufA, Btqkv, (void*)bufB, bqkv, mnull, nullptr, 4 * T, 3 * DM, DM);
        attn4<<<dim3(T), dim3(256), 0, stream>>>(bufB, bufC);
        gemm_bt<1><<<dim3(DM / BN, 4 * T / BM), dim3(256), 0, stream>>>(
            bufC, Bto, (void*)bufA, bo4, mnull, nullptr, 4 * T, DM, DM);
        gemm_bt<2><<<dim3(2 * DM / BN, T / BM), dim3(256), 0, stream>>>(
            bufA, Btg1, (void*)bufC, bg14, mnull, nullptr, T, 2 * DM, 4 * DM);
        gemm_bt<3><<<dim3(DM / BN, T / BM), dim3(256), 0, stream>>>(
            bufC, Btg2, (void*)bufB, bg24, mnull, nullptr, T, DM, 2 * DM);
        resid_ln<<<dim3(T), dim3(256), 0, stream>>>(
            (const float*)bufB, feat + (size_t)t0 * DM, lng, lnb,
            (float*)d_out + (size_t)t0 * DM);
    }
}

// Round 8
// 647.939 us; speedup vs baseline: 1.6855x; 1.0743x over previous
//
#include <hip/hip_runtime.h>
#include <cstdint>
#include <cstddef>

// ---------------- constants ----------------
#define DM   1024          // model dim
#define NT   8192          // B*L tokens
#define HD   256
#define BM 128
#define BN 128
#define BK 64

typedef __attribute__((ext_vector_type(4))) float f32x4;
typedef __attribute__((ext_vector_type(8))) short bf16x8;

#define MF(a_, b_, c_) __builtin_amdgcn_mfma_f32_16x16x32_bf16(a_, b_, c_, 0, 0, 0)

__device__ __forceinline__ unsigned short f2bf(float f) {
    union { float f; uint32_t u; } v; v.f = f;
    return (unsigned short)((v.u + 0x7fffu + ((v.u >> 16) & 1u)) >> 16);
}
__device__ __forceinline__ float bf2f(unsigned short h) {
    union { uint32_t u; float f; } v; v.u = ((uint32_t)h) << 16;
    return v.f;
}

// T1: XCD-chunked bijective blockIdx swizzle (bijective when nwg%8==0).
__device__ __forceinline__ int2 xcd_swizzle_xy() {
    int wid = blockIdx.y * gridDim.x + blockIdx.x;
    const int nwg = gridDim.x * gridDim.y;
    if ((nwg & 7) == 0) {
        const int per = nwg >> 3;
        wid = (wid & 7) * per + (wid >> 3);
    }
    int2 r;
    r.x = wid % gridDim.x;
    r.y = wid / gridDim.x;
    return r;
}

struct Ptr4 { const float* p[4]; };
struct Mask4 { const int* p[4]; };

// ---------------- prep kernels ----------------
__global__ void cvt_f32_to_bf16(const float* __restrict__ src,
                                unsigned short* __restrict__ dst, int n4) {
    int i = blockIdx.x * blockDim.x + threadIdx.x;
    if (i >= n4) return;
    float4 v = reinterpret_cast<const float4*>(src)[i];
    ushort4 o;
    o.x = f2bf(v.x); o.y = f2bf(v.y); o.z = f2bf(v.z); o.w = f2bf(v.w);
    reinterpret_cast<ushort4*>(dst)[i] = o;
}

// src fp32 [K][Nc] row-major  ->  dst bf16 [Nc][K] row-major (transposed)
__global__ void transpose_cvt(const float* __restrict__ src,
                              unsigned short* __restrict__ dst, int K, int Nc) {
    __shared__ float tile[32][33];
    const int n0 = blockIdx.x * 32, k0 = blockIdx.y * 32;
    const int tx = threadIdx.x & 31, ty = threadIdx.x >> 5;   // 32 x 8
#pragma unroll
    for (int i = 0; i < 4; ++i) {
        int k = ty + i * 8;
        tile[k][tx] = src[(size_t)(k0 + k) * Nc + n0 + tx];
    }
    __syncthreads();
#pragma unroll
    for (int i = 0; i < 4; ++i) {
        int n = ty + i * 8;
        dst[(size_t)(n0 + n) * K + k0 + tx] = f2bf(tile[tx][n]);
    }
}

__device__ __forceinline__ void gload16(const void* g, void* l) {
    __builtin_amdgcn_global_load_lds(
        (const __attribute__((address_space(1))) void*)g,
        (__attribute__((address_space(3))) void*)l, 16, 0, 0);
}

// ---------------- 128x128 GEMM, BK=64 + both-sides XOR swizzle ----------------
// LDS tile [128][64] bf16 (128B rows). Physical 16B-unit u' = u ^ (row&7):
// staging keeps linear global_load_lds dest + inverse-swizzled per-lane SOURCE;
// ds_read applies the same XOR -> 2-way bank aliasing (free), 2 barriers / 64-K.
// EPI: 0=(acc+bias)*mask->bf16            (plan A modality projection)
//      1=acc+bias->bf16                   (plan A)
//      2=gelu(acc+bias)->bf16             (MLP1)
//      3=acc+bias->f32                    (MLP2)
//      5=mask*(acc+biasA[col])+bias2->bf16 (fused QKV; col = qk*4096+i*1024+j)
template <int EPI>
__global__ void gemm_bt(const unsigned short* __restrict__ A,
                        const unsigned short* __restrict__ Bt,
                        void* __restrict__ out, Ptr4 bias, Mask4 masks,
                        const float* __restrict__ biasA,
                        int M, int Nc, int K) {
    __shared__ __attribute__((aligned(16))) unsigned short Als[BM * BK];
    __shared__ __attribute__((aligned(16))) unsigned short Bls[BN * BK];
    const int tid = threadIdx.x;
    const int wave = tid >> 6, lane = tid & 63;
    const int2 bxy = xcd_swizzle_xy();
    const int tileM = bxy.y * BM, tileN = bxy.x * BN;
    const int wr = wave >> 1, wc = wave & 1;
    const int la = lane & 15, lh = lane >> 4;

    f32x4 acc[4][4] = {};

    // staging: thread t covers row (t>>3) (+32/chunk), 16B unit (t&7), swizzled source
    const int sr = tid >> 3;
    const int sb = (tid & 7) * 16;
    const int ssw = (sb ^ ((sr & 7) << 4)) >> 1;     // elem offset in row
    const unsigned short* aSrcs[4];
    const unsigned short* bSrcs[4];
#pragma unroll
    for (int c = 0; c < 4; ++c) {
        aSrcs[c] = A + (size_t)(tileM + c * 32 + sr) * K + ssw;
        bSrcs[c] = Bt + (size_t)(tileN + c * 32 + sr) * K + ssw;
    }

    for (int k0 = 0; k0 < K; k0 += BK) {
#pragma unroll
        for (int c = 0; c < 4; ++c)
            gload16(aSrcs[c] + k0, &Als[wave * 512 + c * 2048]);
#pragma unroll
        for (int c = 0; c < 4; ++c)
            gload16(bSrcs[c] + k0, &Bls[wave * 512 + c * 2048]);
        __syncthreads();
#pragma unroll
        for (int ks = 0; ks < 2; ++ks) {
            const int uo = ((ks * 4 + lh) ^ (la & 7)) * 8;   // swizzled elem offset
            bf16x8 af[4], bfr[4];
#pragma unroll
            for (int m = 0; m < 4; ++m)
                af[m] = *reinterpret_cast<const bf16x8*>(&Als[(wr * 64 + m * 16 + la) * BK + uo]);
#pragma unroll
            for (int n = 0; n < 4; ++n)
                bfr[n] = *reinterpret_cast<const bf16x8*>(&Bls[(wc * 64 + n * 16 + la) * BK + uo]);
#pragma unroll
            for (int m = 0; m < 4; ++m)
#pragma unroll
                for (int n = 0; n < 4; ++n)
                    acc[m][n] = MF(af[m], bfr[n], acc[m][n]);
        }
        __syncthreads();
    }

    const int rowT = tileM + wr * 64 + lh * 4;
    const int colT = tileN + wc * 64;
    unsigned short* outB = (unsigned short*)out;
    float* outF = (float*)out;

    float mv[4][4];
    if constexpr (EPI == 0 || EPI == 5) {
        const int* mp = (EPI == 0) ? masks.p[tileN >> 10] : masks.p[(tileN >> 10) & 3];
#pragma unroll
        for (int m = 0; m < 4; ++m)
#pragma unroll
            for (int i = 0; i < 4; ++i)
                mv[m][i] = (float)mp[rowT + m * 16 + i];
    }
    const float* bp = nullptr;
    const float* bp2 = nullptr;
    if constexpr (EPI == 5) bp2 = bias.p[tileN >> 12];
    else bp = bias.p[tileN >> 10];

#pragma unroll
    for (int n = 0; n < 4; ++n) {
        const int gcol = colT + n * 16 + la;
        float bv, bv2 = 0.f;
        if constexpr (EPI == 5) { bv = biasA[gcol]; bv2 = bp2[gcol & (DM - 1)]; }
        else bv = bp[gcol & (DM - 1)];
#pragma unroll
        for (int m = 0; m < 4; ++m) {
#pragma unroll
            for (int i = 0; i < 4; ++i) {
                const int grow = rowT + m * 16 + i;
                float val = acc[m][n][i] + bv;
                if constexpr (EPI == 0) {
                    val *= mv[m][i];
                    outB[(size_t)grow * Nc + gcol] = f2bf(val);
                } else if constexpr (EPI == 1) {
                    outB[(size_t)grow * Nc + gcol] = f2bf(val);
                } else if constexpr (EPI == 2) {
                    val = 0.5f * val * (1.0f + erff(val * 0.70710678118654752f));
                    outB[(size_t)grow * Nc + gcol] = f2bf(val);
                } else if constexpr (EPI == 3) {
                    outF[(size_t)grow * Nc + gcol] = val;
                } else { // EPI == 5
                    val = mv[m][i] * val + bv2;
                    outB[(size_t)grow * Nc + gcol] = f2bf(val);
                }
            }
        }
    }
}

// ---------------- weight-fusion prep GEMM (same BK=64 core, strided) ----------------
// TSTORE=true  (P1): C[(i,k),(qk,j)] = (W_i @ W_qk)[k,j] -> Btf[(qk*4096+i*1024+j), k]
// TSTORE=false (P2): per-z: C[c,k] = (Wo@Wg1_z)^T -> out[c*ldc + z*cZstride + k]
template <bool TSTORE>
__global__ void gemm_prep(const unsigned short* __restrict__ A0, int lda, int aZoff,
                          const unsigned short* __restrict__ Bt, int ldb,
                          unsigned short* __restrict__ out, int ldc, int cZstride,
                          int K) {
    __shared__ __attribute__((aligned(16))) unsigned short Als[BM * BK];
    __shared__ __attribute__((aligned(16))) unsigned short Bls[BN * BK];
    const unsigned short* A = A0 + (size_t)blockIdx.z * aZoff;
    const int tid = threadIdx.x;
    const int wave = tid >> 6, lane = tid & 63;
    const int2 bxy = xcd_swizzle_xy();
    const int tileM = bxy.y * BM, tileN = bxy.x * BN;
    const int wr = wave >> 1, wc = wave & 1;
    const int la = lane & 15, lh = lane >> 4;

    f32x4 acc[4][4] = {};

    const int sr = tid >> 3;
    const int sb = (tid & 7) * 16;
    const int ssw = (sb ^ ((sr & 7) << 4)) >> 1;
    const unsigned short* aSrcs[4];
    const unsigned short* bSrcs[4];
#pragma unroll
    for (int c = 0; c < 4; ++c) {
        aSrcs[c] = A + (size_t)(tileM + c * 32 + sr) * lda + ssw;
        bSrcs[c] = Bt + (size_t)(tileN + c * 32 + sr) * ldb + ssw;
    }

    for (int k0 = 0; k0 < K; k0 += BK) {
#pragma unroll
        for (int c = 0; c < 4; ++c)
            gload16(aSrcs[c] + k0, &Als[wave * 512 + c * 2048]);
#pragma unroll
        for (int c = 0; c < 4; ++c)
            gload16(bSrcs[c] + k0, &Bls[wave * 512 + c * 2048]);
        __syncthreads();
#pragma unroll
        for (int ks = 0; ks < 2; ++ks) {
            const int uo = ((ks * 4 + lh) ^ (la & 7)) * 8;
            bf16x8 af[4], bfr[4];
#pragma unroll
            for (int m = 0; m < 4; ++m)
                af[m] = *reinterpret_cast<const bf16x8*>(&Als[(wr * 64 + m * 16 + la) * BK + uo]);
#pragma unroll
            for (int n = 0; n < 4; ++n)
                bfr[n] = *reinterpret_cast<const bf16x8*>(&Bls[(wc * 64 + n * 16 + la) * BK + uo]);
#pragma unroll
            for (int m = 0; m < 4; ++m)
#pragma unroll
                for (int n = 0; n < 4; ++n)
                    acc[m][n] = MF(af[m], bfr[n], acc[m][n]);
        }
        __syncthreads();
    }

    const int rowT = tileM + wr * 64 + lh * 4;
    const int colT = tileN + wc * 64;

#pragma unroll
    for (int n = 0; n < 4; ++n) {
        const int gcol = colT + n * 16 + la;
#pragma unroll
        for (int m = 0; m < 4; ++m) {
            if constexpr (TSTORE) {
                const int g0 = rowT + m * 16;          // (i,k): i=g0>>10, k=g0&1023
                ushort4 o4;
                o4.x = f2bf(acc[m][n][0]);
                o4.y = f2bf(acc[m][n][1]);
                o4.z = f2bf(acc[m][n][2]);
                o4.w = f2bf(acc[m][n][3]);
                const size_t drow = ((size_t)(gcol >> 10) << 12) +
                                    ((size_t)(g0 >> 10) << 10) + (gcol & 1023);
                *reinterpret_cast<ushort4*>(out + drow * 1024 + (g0 & 1023)) = o4;
            } else {
#pragma unroll
                for (int i = 0; i < 4; ++i) {
                    const int grow = rowT + m * 16 + i;
                    out[(size_t)grow * ldc + (size_t)blockIdx.z * cZstride + gcol] =
                        f2bf(acc[m][n][i]);
                }
            }
        }
    }
}

// ---------------- bias folding ----------------
__global__ void fuse_biasA(Ptr4 bmods, const unsigned short* __restrict__ Btqkv,
                           float* __restrict__ biasA) {
    const int o = blockIdx.x * 4 + (threadIdx.x >> 6);
    const int lane = threadIdx.x & 63;
    const int qk = o >> 12, im = (o >> 10) & 3, j = o & 1023;
    const float* b = bmods.p[im];
    const unsigned short* wrow = Btqkv + ((size_t)(qk << 10) + j) * 1024;
    float s = 0.f;
    for (int t = lane; t < 1024; t += 64) s += b[t] * bf2f(wrow[t]);
#pragma unroll
    for (int off = 32; off >= 1; off >>= 1) s += __shfl_xor(s, off, 64);
    if (lane == 0) biasA[o] = s;
}

__global__ void fuse_biasH(const float* __restrict__ bo, const float* __restrict__ bg1,
                           const unsigned short* __restrict__ Btg1,
                           float* __restrict__ biasH) {
    const int c = blockIdx.x * 4 + (threadIdx.x >> 6);
    const int lane = threadIdx.x & 63;
    const unsigned short* row = Btg1 + (size_t)c * 4096;
    float s = 0.f;
    for (int t = lane; t < 4096; t += 64) s += bo[t & 1023] * bf2f(row[t]);
#pragma unroll
    for (int off = 32; off >= 1; off >>= 1) s += __shfl_xor(s, off, 64);
    if (lane == 0) biasH[c] = s + bg1[c];
}

// ---------------- tiny 4-token attention, fused-QKV layout ----------------
__global__ void attn4F(const unsigned short* __restrict__ qkvF,
                       unsigned short* __restrict__ ctx) {
    const int n = blockIdx.x;
    const int h = threadIdx.x >> 6;
    const int lane = threadIdx.x & 63;
    const size_t base = (size_t)n * 12288 + h * HD + lane * 4;

    float q[4][4], k[4][4], v[4][4];
#pragma unroll
    for (int m = 0; m < 4; ++m) {
        ushort4 uq = *reinterpret_cast<const ushort4*>(&qkvF[base + m * 1024]);
        ushort4 uk = *reinterpret_cast<const ushort4*>(&qkvF[base + m * 1024 + 4096]);
        ushort4 uv = *reinterpret_cast<const ushort4*>(&qkvF[base + m * 1024 + 8192]);
        q[m][0] = bf2f(uq.x); q[m][1] = bf2f(uq.y); q[m][2] = bf2f(uq.z); q[m][3] = bf2f(uq.w);
        k[m][0] = bf2f(uk.x); k[m][1] = bf2f(uk.y); k[m][2] = bf2f(uk.z); k[m][3] = bf2f(uk.w);
        v[m][0] = bf2f(uv.x); v[m][1] = bf2f(uv.y); v[m][2] = bf2f(uv.z); v[m][3] = bf2f(uv.w);
    }

    float s[4][4];
#pragma unroll
    for (int qi = 0; qi < 4; ++qi)
#pragma unroll
        for (int ki = 0; ki < 4; ++ki)
            s[qi][ki] = q[qi][0] * k[ki][0] + q[qi][1] * k[ki][1] +
                        q[qi][2] * k[ki][2] + q[qi][3] * k[ki][3];
#pragma unroll
    for (int off = 32; off >= 1; off >>= 1) {
#pragma unroll
        for (int qi = 0; qi < 4; ++qi)
#pragma unroll
            for (int ki = 0; ki < 4; ++ki)
                s[qi][ki] += __shfl_xor(s[qi][ki], off, 64);
    }

#pragma unroll
    for (int qi = 0; qi < 4; ++qi) {
        float s0 = s[qi][0] * 0.0625f, s1 = s[qi][1] * 0.0625f;
        float s2 = s[qi][2] * 0.0625f, s3 = s[qi][3] * 0.0625f;
        float mx = fmaxf(fmaxf(s0, s1), fmaxf(s2, s3));
        float e0 = __expf(s0 - mx), e1 = __expf(s1 - mx);
        float e2 = __expf(s2 - mx), e3 = __expf(s3 - mx);
        float inv = 1.0f / (e0 + e1 + e2 + e3);
        e0 *= inv; e1 *= inv; e2 *= inv; e3 *= inv;
        ushort4 o;
        o.x = f2bf(e0 * v[0][0] + e1 * v[1][0] + e2 * v[2][0] + e3 * v[3][0]);
        o.y = f2bf(e0 * v[0][1] + e1 * v[1][1] + e2 * v[2][1] + e3 * v[3][1]);
        o.z = f2bf(e0 * v[0][2] + e1 * v[1][2] + e2 * v[2][2] + e3 * v[3][2]);
        o.w = f2bf(e0 * v[0][3] + e1 * v[1][3] + e2 * v[2][3] + e3 * v[3][3]);
        *reinterpret_cast<ushort4*>(&ctx[(size_t)n * 4096 + qi * 1024 + h * HD + lane * 4]) = o;
    }
}

// ---------------- tiny 4-token attention, legacy layout (plan A) ----------------
__global__ void attn4(const unsigned short* __restrict__ qkv,
                      unsigned short* __restrict__ ctx) {
    const int n = blockIdx.x;
    const int h = threadIdx.x >> 6;
    const int lane = threadIdx.x & 63;
    const size_t base = (size_t)n * 4 * 3072 + h * HD + lane * 4;

    float q[4][4], k[4][4], v[4][4];
#pragma unroll
    for (int m = 0; m < 4; ++m) {
        ushort4 uq = *reinterpret_cast<const ushort4*>(&qkv[base + (size_t)m * 3072]);
        ushort4 uk = *reinterpret_cast<const ushort4*>(&qkv[base + (size_t)m * 3072 + 1024]);
        ushort4 uv = *reinterpret_cast<const ushort4*>(&qkv[base + (size_t)m * 3072 + 2048]);
        q[m][0] = bf2f(uq.x); q[m][1] = bf2f(uq.y); q[m][2] = bf2f(uq.z); q[m][3] = bf2f(uq.w);
        k[m][0] = bf2f(uk.x); k[m][1] = bf2f(uk.y); k[m][2] = bf2f(uk.z); k[m][3] = bf2f(uk.w);
        v[m][0] = bf2f(uv.x); v[m][1] = bf2f(uv.y); v[m][2] = bf2f(uv.z); v[m][3] = bf2f(uv.w);
    }

    float s[4][4];
#pragma unroll
    for (int qi = 0; qi < 4; ++qi)
#pragma unroll
        for (int ki = 0; ki < 4; ++ki)
            s[qi][ki] = q[qi][0] * k[ki][0] + q[qi][1] * k[ki][1] +
                        q[qi][2] * k[ki][2] + q[qi][3] * k[ki][3];
#pragma unroll
    for (int off = 32; off >= 1; off >>= 1) {
#pragma unroll
        for (int qi = 0; qi < 4; ++qi)
#pragma unroll
            for (int ki = 0; ki < 4; ++ki)
                s[qi][ki] += __shfl_xor(s[qi][ki], off, 64);
    }

#pragma unroll
    for (int qi = 0; qi < 4; ++qi) {
        float s0 = s[qi][0] * 0.0625f, s1 = s[qi][1] * 0.0625f;
        float s2 = s[qi][2] * 0.0625f, s3 = s[qi][3] * 0.0625f;
        float mx = fmaxf(fmaxf(s0, s1), fmaxf(s2, s3));
        float e0 = __expf(s0 - mx), e1 = __expf(s1 - mx);
        float e2 = __expf(s2 - mx), e3 = __expf(s3 - mx);
        float inv = 1.0f / (e0 + e1 + e2 + e3);
        e0 *= inv; e1 *= inv; e2 *= inv; e3 *= inv;
        ushort4 o;
        o.x = f2bf(e0 * v[0][0] + e1 * v[1][0] + e2 * v[2][0] + e3 * v[3][0]);
        o.y = f2bf(e0 * v[0][1] + e1 * v[1][1] + e2 * v[2][1] + e3 * v[3][1]);
        o.z = f2bf(e0 * v[0][2] + e1 * v[1][2] + e2 * v[2][2] + e3 * v[3][2]);
        o.w = f2bf(e0 * v[0][3] + e1 * v[1][3] + e2 * v[2][3] + e3 * v[3][3]);
        *reinterpret_cast<ushort4*>(&ctx[(size_t)(n * 4 + qi) * 1024 + h * HD + lane * 4]) = o;
    }
}

// ---------------- residual + LayerNorm ----------------
__global__ void resid_ln(const float* __restrict__ cons, const float* __restrict__ feat,
                         const float* __restrict__ g, const float* __restrict__ b,
                         float* __restrict__ out) {
    const int row = blockIdx.x;
    const int t = threadIdx.x;
    const size_t base = (size_t)row * DM + t * 4;
    float4 c = *reinterpret_cast<const float4*>(&cons[base]);
    float4 f = *reinterpret_cast<const float4*>(&feat[base]);
    float y0 = c.x + f.x, y1 = c.y + f.y, y2 = c.z + f.z, y3 = c.w + f.w;
    float sum = y0 + y1 + y2 + y3;
    float sq = y0 * y0 + y1 * y1 + y2 * y2 + y3 * y3;
#pragma unroll
    for (int off = 32; off >= 1; off >>= 1) {
        sum += __shfl_xor(sum, off, 64);
        sq += __shfl_xor(sq, off, 64);
    }
    __shared__ float rs[4], rq[4];
    const int wv = t >> 6, ln = t & 63;
    if (ln == 0) { rs[wv] = sum; rq[wv] = sq; }
    __syncthreads();
    sum = rs[0] + rs[1] + rs[2] + rs[3];
    sq = rq[0] + rq[1] + rq[2] + rq[3];
    const float mu = sum * (1.0f / DM);
    const float var = sq * (1.0f / DM) - mu * mu;
    const float rstd = rsqrtf(var + 1e-5f);
    float4 gg = *reinterpret_cast<const float4*>(&g[t * 4]);
    float4 bb = *reinterpret_cast<const float4*>(&b[t * 4]);
    float4 o;
    o.x = (y0 - mu) * rstd * gg.x + bb.x;
    o.y = (y1 - mu) * rstd * gg.y + bb.y;
    o.z = (y2 - mu) * rstd * gg.z + bb.z;
    o.w = (y3 - mu) * rstd * gg.w + bb.w;
    *reinterpret_cast<float4*>(&out[base]) = o;
}

// ---------------- launch ----------------
extern "C" void kernel_launch(void* const* d_in, const int* in_sizes, int n_in,
                              void* d_out, int out_size, void* d_ws, size_t ws_size,
                              hipStream_t stream) {
    (void)in_sizes; (void)n_in; (void)out_size;
    const float* feat = (const float*)d_in[0];
    const int* am = (const int*)d_in[1];
    const int* dmk = (const int*)d_in[2];
    const int* em = (const int*)d_in[3];
    const int* hmk = (const int*)d_in[4];
    const float* Wa = (const float*)d_in[5];  const float* ba = (const float*)d_in[6];
    const float* Wd = (const float*)d_in[7];  const float* bd = (const float*)d_in[8];
    const float* We = (const float*)d_in[9];  const float* be = (const float*)d_in[10];
    const float* Wh = (const float*)d_in[11]; const float* bh = (const float*)d_in[12];
    const float* Wq = (const float*)d_in[13]; const float* bq = (const float*)d_in[14];
    const float* Wk = (const float*)d_in[15]; const float* bk = (const float*)d_in[16];
    const float* Wv = (const float*)d_in[17]; const float* bv = (const float*)d_in[18];
    const float* Wo = (const float*)d_in[19]; const float* bo = (const float*)d_in[20];
    const float* Wg1 = (const float*)d_in[21]; const float* bg1 = (const float*)d_in[22];
    const float* Wg2 = (const float*)d_in[23]; const float* bg2 = (const float*)d_in[24];
    const float* lng = (const float*)d_in[25]; const float* lnb = (const float*)d_in[26];

    char* ws = (char*)d_ws;
    size_t off = 0;
    auto take = [&](size_t bytes) -> char* {
        char* r = ws + off;
        off = (off + bytes + 255) & ~(size_t)255;
        return r;
    };
    // ---- fixed allocations (~97 MB) ----
    unsigned short* featB = (unsigned short*)take((size_t)NT * DM * 2);
    unsigned short* Btqkv = (unsigned short*)take((size_t)3 * DM * DM * 2);
    unsigned short* Btg1  = (unsigned short*)take((size_t)2 * DM * 4 * DM * 2);
    unsigned short* Btg2  = (unsigned short*)take((size_t)DM * 2 * DM * 2);
    unsigned short* Wcat  = (unsigned short*)take((size_t)4 * DM * DM * 2);
    unsigned short* Wo_bf = (unsigned short*)take((size_t)DM * DM * 2);
    unsigned short* Btf   = (unsigned short*)take((size_t)12 * DM * DM * 2);
    unsigned short* Btm1  = (unsigned short*)take((size_t)8 * DM * DM * 2);
    float* biasA          = (float*)take((size_t)12 * DM * 4);
    float* biasH          = (float*)take((size_t)2 * DM * 4);
    const size_t fixed = off;

    // shared prep
    cvt_f32_to_bf16<<<dim3((NT * DM / 4 + 255) / 256), dim3(256), 0, stream>>>(
        feat, featB, NT * DM / 4);
    auto tl = [&](const float* src, unsigned short* dst, int K, int Nc) {
        transpose_cvt<<<dim3(Nc / 32, K / 32), dim3(256), 0, stream>>>(src, dst, K, Nc);
    };
    tl(Wq, Btqkv, DM, DM);
    tl(Wk, Btqkv + (size_t)DM * DM, DM, DM);
    tl(Wv, Btqkv + (size_t)2 * DM * DM, DM, DM);
    tl(Wg1, Btg1, 4 * DM, 2 * DM);
    tl(Wg2, Btg2, 2 * DM, DM);

    Ptr4 bmods{{ba, bd, be, bh}};
    Ptr4 bqkv{{bq, bk, bv, nullptr}};
    Ptr4 bH{{biasH, biasH + DM, nullptr, nullptr}};
    Ptr4 bg24{{bg2, nullptr, nullptr, nullptr}};
    Mask4 mnull{{nullptr, nullptr, nullptr, nullptr}};

    // ---- plan B sizing: ctx full (67.1M) + qkvF chunk / h (regH) ----
    const size_t ctxBytes = (size_t)NT * 4096 * 2;
    const size_t hBytes = (size_t)NT * 2048 * 2 + 512;
    int T2 = 0;
    {
        const int cands[4] = {8192, 4096, 2048, 1024};
        for (int ci = 0; ci < 4; ++ci) {
            int c = cands[ci];
            size_t chunkB = (size_t)c * 24576 + 512;
            size_t regHB = chunkB > hBytes ? chunkB : hBytes;
            if (fixed + ctxBytes + 256 + regHB + 4096 <= ws_size) { T2 = c; break; }
        }
    }

    if (T2 > 0) {
        char* regX = take(ctxBytes);
        size_t chunkB = (size_t)T2 * 24576 + 512;
        char* regH = take(chunkB > hBytes ? chunkB : hBytes);
        unsigned short* ctx = (unsigned short*)regX;    // ctx bf16 [NT][4096]
        float* cons = (float*)regX;                     // consensus f32 (aliases ctx)
        unsigned short* h = (unsigned short*)regH;      // gelu-h bf16 [NT][2048]
        unsigned short* qkvF = (unsigned short*)regH;   // qkv chunk bf16 [T2][12288]

        // fused-weight prep
        cvt_f32_to_bf16<<<dim3(DM * DM / 4 / 256), dim3(256), 0, stream>>>(Wa, Wcat, DM * DM / 4);
        cvt_f32_to_bf16<<<dim3(DM * DM / 4 / 256), dim3(256), 0, stream>>>(Wd, Wcat + (size_t)DM * DM, DM * DM / 4);
        cvt_f32_to_bf16<<<dim3(DM * DM / 4 / 256), dim3(256), 0, stream>>>(We, Wcat + (size_t)2 * DM * DM, DM * DM / 4);
        cvt_f32_to_bf16<<<dim3(DM * DM / 4 / 256), dim3(256), 0, stream>>>(Wh, Wcat + (size_t)3 * DM * DM, DM * DM / 4);
        cvt_f32_to_bf16<<<dim3(DM * DM / 4 / 256), dim3(256), 0, stream>>>(Wo, Wo_bf, DM * DM / 4);
        gemm_prep<true><<<dim3(24, 32, 1), dim3(256), 0, stream>>>(
            Wcat, DM, 0, Btqkv, DM, Btf, 0, 0, DM);
        gemm_prep<false><<<dim3(8, 16, 4), dim3(256), 0, stream>>>(
            Btg1, 4 * DM, DM, Wo_bf, DM, Btm1, 4 * DM, DM, DM);
        fuse_biasA<<<dim3(12 * DM / 4), dim3(256), 0, stream>>>(bmods, Btqkv, biasA);
        fuse_biasH<<<dim3(2 * DM / 4), dim3(256), 0, stream>>>(bo, bg1, Btg1, biasH);

        // fused QKV + attention, chunked over tokens
        for (int t0 = 0; t0 < NT; t0 += T2) {
            Mask4 mk{{am + t0, dmk + t0, em + t0, hmk + t0}};
            gemm_bt<5><<<dim3(96, T2 / BM), dim3(256), 0, stream>>>(
                featB + (size_t)t0 * DM, Btf, (void*)qkvF, bqkv, mk, biasA,
                T2, 12 * DM, DM);
            attn4F<<<dim3(T2), dim3(256), 0, stream>>>(qkvF, ctx + (size_t)t0 * 4096);
        }
        // MLP1 (fused Wo@Wg1) + GELU: h[NT][2048] = gelu(ctx @ Btm1^T + biasH)
        gemm_bt<2><<<dim3(16, NT / BM), dim3(256), 0, stream>>>(
            ctx, Btm1, (void*)h, bH, mnull, nullptr, NT, 2 * DM, 4 * DM);
        // MLP2: cons f32 [NT][1024]
        gemm_bt<3><<<dim3(8, NT / BM), dim3(256), 0, stream>>>(
            h, Btg2, (void*)cons, bg24, mnull, nullptr, NT, DM, 2 * DM);
        // residual + LayerNorm
        resid_ln<<<dim3(NT), dim3(256), 0, stream>>>(cons, feat, lng, lnb, (float*)d_out);
        return;
    }

    // ---- plan A fallback (fully-chunked unfused pipeline) ----
    unsigned short* Bt1 = (unsigned short*)take((size_t)4 * DM * DM * 2);
    unsigned short* Bto = (unsigned short*)take((size_t)DM * DM * 2);
    tl(Wa, Bt1, DM, DM);
    tl(Wd, Bt1 + (size_t)DM * DM, DM, DM);
    tl(We, Bt1 + (size_t)2 * DM * DM, DM, DM);
    tl(Wh, Bt1 + (size_t)3 * DM * DM, DM, DM);
    tl(Wo, Bto, DM, DM);

    Ptr4 b1{{ba, bd, be, bh}};
    Ptr4 bo4{{bo, nullptr, nullptr, nullptr}};
    Ptr4 bg14{{bg1, bg1 + DM, nullptr, nullptr}};

    const size_t avail = (ws_size > off) ? (ws_size - off) : 0;
    int T = 2048;
    while (T > 128 && ((size_t)T * 40960 + 4096) > avail) T >>= 1;
    unsigned short* bufA = (unsigned short*)take((size_t)T * 4096 * 2);
    unsigned short* bufB = (unsigned short*)take((size_t)T * 4 * 3072 * 2);
    unsigned short* bufC = (unsigned short*)take((size_t)T * 4 * 1024 * 2);

    const int nch = NT / T;
    for (int c = 0; c < nch; ++c) {
        const int t0 = c * T;
        Mask4 mk{{am + t0, dmk + t0, em + t0, hmk + t0}};
        gemm_bt<0><<<dim3(4 * DM / BN, T / BM), dim3(256), 0, stream>>>(
            featB + (size_t)t0 * DM, Bt1, (void*)bufA, b1, mk, nullptr, T, 4 * DM, DM);
        gemm_bt<1><<<dim3(3 * DM / BN, 4 * T / BM), dim3(256), 0, stream>>>(
            bufA, Btqkv, (void*)bufB, bqkv, mnull, nullptr, 4 * T, 3 * DM, DM);
        attn4<<<dim3(T), dim3(256), 0, stream>>>(bufB, bufC);
        gemm_bt<1><<<dim3(DM / BN, 4 * T / BM), dim3(256), 0, stream>>>(
            bufC, Bto, (void*)bufA, bo4, mnull, nullptr, 4 * T, DM, DM);
        gemm_bt<2><<<dim3(2 * DM / BN, T / BM), dim3(256), 0, stream>>>(
            bufA, Btg1, (void*)bufC, bg14, mnull, nullptr, T, 2 * DM, 4 * DM);
        gemm_bt<3><<<dim3(DM / BN, T / BM), dim3(256), 0, stream>>>(
            bufC, Btg2, (void*)bufB, bg24, mnull, nullptr, T, DM, 2 * DM);
        resid_ln<<<dim3(T), dim3(256), 0, stream>>>(
            (const float*)bufB, feat + (size_t)t0 * DM, lng, lnb,
            (float*)d_out + (size_t)t0 * DM);
    }
}